// Round 3
// baseline (601.783 us; speedup 1.0000x reference)
//
#include <hip/hip_runtime.h>
#include <hip/hip_bf16.h>
#include <stdint.h>

#define B_ 8
#define L_ 1024
#define H_ 768
#define E_ 16
#define W_ 504
#define DFF_ 512
#define N_ 5982
#define NE_ (N_*E_)    // 95712 candidates per batch
#define BNE_ (B_*NE_)  // 765696
#define MAXK48 0x0000FFFFFFFFFFFFull
#define PT_ 24         // per-thread elements: 24*256 = 6144 >= N_

typedef unsigned long long u64;
typedef unsigned int u32;

__device__ __forceinline__ int rowstart_of(int s){
    int s0 = W_ - 11; // 493
    if (s <= s0) return 12*s;
    int t = s - s0;
    return 12*s0 + t*11 - (t*(t-1))/2;
}

// ---------------- span tables ----------------
__global__ void k_tables(int* starts, int* ends){
    int s = blockIdx.x*64 + threadIdx.x;
    if (s >= W_) return;
    int rs = rowstart_of(s);
    int cnt = min(12, W_ - s);
    for (int i = 0; i < cnt; i++){ starts[rs+i] = s; ends[rs+i] = s+i; }
}

// ---------------- token lists: parallel build + deterministic per-word sort ----------------
__global__ void k_toklist(const int* __restrict__ tm, const int* __restrict__ wi,
                          int* __restrict__ tok, int* __restrict__ tokc){
    int i = blockIdx.x*256 + threadIdx.x;
    if (i >= B_*L_) return;
    int w = wi[i];
    if (tm[i] == 1 && w >= 0 && w < W_){
        int b = i / L_;
        int bw = b*W_ + w;
        int pos = atomicAdd(&tokc[bw], 1);
        if (pos < 4) tok[bw*4 + pos] = i - b*L_;
    }
}

__global__ void k_toksort(int* __restrict__ tok, const int* __restrict__ tokc){
    int bw = blockIdx.x*256 + threadIdx.x;
    if (bw >= B_*W_) return;
    int c = min(tokc[bw], 4);
    int v[4];
    for (int k = 0; k < c; k++) v[k] = tok[bw*4 + k];
    for (int a = 1; a < c; a++){ int x = v[a]; int j = a-1; while (j >= 0 && v[j] > x){ v[j+1] = v[j]; j--; } v[j+1] = x; }
    for (int k = 0; k < c; k++) tok[bw*4 + k] = v[k];
}

// ---------------- word mean pooling (gather, deterministic) ----------------
__global__ void k_pool(const float* __restrict__ hs,
                       const int* __restrict__ tok, const int* __restrict__ tokc,
                       float* __restrict__ wemb){
    int idx = blockIdx.x*256 + threadIdx.x;      // over B*W*H
    if (idx >= B_*W_*H_) return;
    int h = idx % H_; int bw = idx / H_; int b = bw / W_;
    int c = tokc[bw]; int cc = min(c, 4);
    double s = 0.0;
    for (int k = 0; k < cc; k++){
        int l = tok[bw*4 + k];
        s += (double)hs[((size_t)(b*L_ + l))*H_ + h];
    }
    float denom = (float)max(c, 1);
    wemb[idx] = (float)(s / (double)denom);
}

// ---------------- entity positions: literal stable scan ----------------
__global__ void k_entpos(const int* __restrict__ ent_mask, int* __restrict__ ent_pos){
    int b = blockIdx.x;
    if (threadIdx.x != 0) return;
    int c = 0;
    for (int l = 0; l < L_ && c < E_; l++) if (ent_mask[b*L_ + l] == 1) ent_pos[b*E_ + c++] = l;
    for (int l = 0; l < L_ && c < E_; l++) if (ent_mask[b*L_ + l] != 1) ent_pos[b*E_ + c++] = l;
}

// ---------------- entity MLP layer 1 ----------------
__global__ void k_ent1(const float* __restrict__ hs, const int* __restrict__ ent_pos,
                       const float* __restrict__ w1, const float* __restrict__ b1,
                       float* __restrict__ hidg){
    __shared__ float x[H_];
    int blk = blockIdx.x;            // 256 blocks: be*2 + half
    int be = blk >> 1; int half = blk & 1;
    int b = be >> 4;
    int tid = threadIdx.x;
    int pos = ent_pos[be];
    const float* xp = hs + ((size_t)b*L_ + pos)*H_;
    for (int j = tid; j < H_; j += 256) x[j] = xp[j];
    __syncthreads();
    int d = half*256 + tid;
    float a0=0.f,a1=0.f,a2=0.f,a3=0.f;
    const float* wp = w1 + d;
    #pragma unroll 4
    for (int h = 0; h < H_; h += 4){
        a0 += x[h+0]*wp[(size_t)(h+0)*DFF_];
        a1 += x[h+1]*wp[(size_t)(h+1)*DFF_];
        a2 += x[h+2]*wp[(size_t)(h+2)*DFF_];
        a3 += x[h+3]*wp[(size_t)(h+3)*DFF_];
    }
    float acc = ((a0+a1)+(a2+a3)) + b1[d];
    hidg[(size_t)be*DFF_ + d] = acc > 0.f ? acc : 0.01f*acc;
}

// ---------------- entity MLP layer 2 ----------------
__global__ void k_ent2(const float* __restrict__ hidg,
                       const float* __restrict__ w2, const float* __restrict__ b2,
                       float* __restrict__ ent_vec){
    __shared__ float hsd[DFF_];
    int blk = blockIdx.x;            // 384 blocks: be*3 + third
    int be = blk / 3; int third = blk % 3;
    int tid = threadIdx.x;
    const float* hp = hidg + (size_t)be*DFF_;
    for (int j = tid; j < DFF_; j += 256) hsd[j] = hp[j];
    __syncthreads();
    int j = third*256 + tid;
    float a0=0.f,a1=0.f,a2=0.f,a3=0.f;
    const float* wp = w2 + j;
    #pragma unroll 4
    for (int d = 0; d < DFF_; d += 4){
        a0 += hsd[d+0]*wp[(size_t)(d+0)*H_];
        a1 += hsd[d+1]*wp[(size_t)(d+1)*H_];
        a2 += hsd[d+2]*wp[(size_t)(d+2)*H_];
        a3 += hsd[d+3]*wp[(size_t)(d+3)*H_];
    }
    ent_vec[(size_t)be*H_ + j] = ((a0+a1)+(a2+a3)) + b2[j];
}

// ---------------- M[b] = span_w2 @ ent_vec[b]^T (fp64, decode-critical) ----------------
__global__ void k_M(const float* __restrict__ span_w2, const float* __restrict__ ent_vec,
                    float* __restrict__ M){
    int blk = blockIdx.x; int b = blk/32; int dbase = (blk%32)*16;
    int tid = threadIdx.x; int d = dbase + (tid>>4); int e = tid&15;
    const float* ev = ent_vec + ((size_t)b*E_ + e)*H_;
    const float* wr = span_w2 + (size_t)d*H_;
    double p0=0.0, p1=0.0;
    for (int h = 0; h < H_; h += 2){
        p0 += (double)wr[h]*(double)ev[h];
        p1 += (double)wr[h+1]*(double)ev[h+1];
    }
    M[((size_t)b*DFF_ + d)*E_ + e] = (float)(p0+p1);
}

__global__ void k_c(const float* __restrict__ span_b2, const float* __restrict__ ent_vec,
                    float* __restrict__ cvec){
    int i = blockIdx.x*blockDim.x + threadIdx.x;
    if (i >= B_*E_) return;
    const float* ev = ent_vec + (size_t)i*H_;
    double acc = 0.0;
    for (int h = 0; h < H_; h++) acc += (double)span_b2[h]*(double)ev[h];
    cvec[i] = (float)acc;
}

// ---------------- P/Q projection: tiled fp32 GEMM, 64x64 tiles, 2 batches per pass ----------------
__global__ void k_pq(const float* __restrict__ wemb, const float* __restrict__ w1,
                     float* __restrict__ PQ, int b0){
    __shared__ float As[16][68];   // [k][row], +4 pad keeps 16B alignment
    __shared__ float Bs[16][68];   // [k][col]
    int bx = blockIdx.x & 15;      // col tile
    int by = blockIdx.x >> 4;      // row tile (0..15)
    int tid = threadIdx.x;
    int tm = tid >> 4, tn = tid & 15;
    const float* A0 = wemb + (size_t)b0*W_*H_;
    int colbase = bx*64;
    const float* Bbase = (colbase < DFF_) ? w1 : (w1 + (size_t)H_*DFF_);
    int bcol0 = (colbase < DFF_) ? colbase : (colbase - DFF_);
    float acc[4][4] = {{0.f}};
    int ar = tid >> 2, akq = tid & 3;            // A: row, k-quad
    int bkk = tid >> 4, bcq = tid & 15;          // B: k, col-quad
    for (int k0 = 0; k0 < H_; k0 += 16){
        {
            int gr = by*64 + ar;
            float4 av;
            if (gr < 1008) av = *(const float4*)(A0 + (size_t)gr*H_ + k0 + akq*4);
            else av = make_float4(0.f,0.f,0.f,0.f);
            As[akq*4+0][ar] = av.x; As[akq*4+1][ar] = av.y;
            As[akq*4+2][ar] = av.z; As[akq*4+3][ar] = av.w;
        }
        {
            float4 bv = *(const float4*)(Bbase + (size_t)(k0+bkk)*DFF_ + bcol0 + bcq*4);
            Bs[bkk][bcq*4+0] = bv.x; Bs[bkk][bcq*4+1] = bv.y;
            Bs[bkk][bcq*4+2] = bv.z; Bs[bkk][bcq*4+3] = bv.w;
        }
        __syncthreads();
        #pragma unroll
        for (int kk = 0; kk < 16; kk++){
            float4 a = *(const float4*)&As[kk][tm*4];
            float4 bv = *(const float4*)&Bs[kk][tn*4];
            acc[0][0] += a.x*bv.x; acc[0][1] += a.x*bv.y; acc[0][2] += a.x*bv.z; acc[0][3] += a.x*bv.w;
            acc[1][0] += a.y*bv.x; acc[1][1] += a.y*bv.y; acc[1][2] += a.y*bv.z; acc[1][3] += a.y*bv.w;
            acc[2][0] += a.z*bv.x; acc[2][1] += a.z*bv.y; acc[2][2] += a.z*bv.z; acc[2][3] += a.z*bv.w;
            acc[3][0] += a.w*bv.x; acc[3][1] += a.w*bv.y; acc[3][2] += a.w*bv.z; acc[3][3] += a.w*bv.w;
        }
        __syncthreads();
    }
    #pragma unroll
    for (int r = 0; r < 4; r++){
        int gr = by*64 + tm*4 + r;
        if (gr < 1008){
            float4 ov = make_float4(acc[r][0], acc[r][1], acc[r][2], acc[r][3]);
            *(float4*)(PQ + (size_t)gr*1024 + colbase + tn*4) = ov;
        }
    }
}

// ---------------- logits: one block (256 thr) per (bl, start s); M held in registers ----------------
__global__ void k_logits(const float* __restrict__ PQ, const float* __restrict__ Mmat,
                         const float* __restrict__ cvec, const float* __restrict__ span_b1,
                         float* __restrict__ logits, float* __restrict__ outL, int b0){
    __shared__ float Ps[DFF_];
    __shared__ float hid[DFF_];
    __shared__ double red[256];
    __shared__ float csh[E_];
    int blk = blockIdx.x;            // 2*W_ blocks
    int bl = blk / W_; int s = blk - bl*W_;
    int b = b0 + bl;
    int tid = threadIdx.x;
    int ee = tid & 15; int g = tid >> 4;   // 16 groups x 32 d
    float Mreg[32];
    {
        const float* Mp = Mmat + (size_t)b*DFF_*E_ + (size_t)(g*32)*E_ + ee;
        #pragma unroll
        for (int i = 0; i < 32; i++) Mreg[i] = Mp[(size_t)i*E_];
    }
    const float* P = PQ + ((size_t)(bl*W_ + s))*1024;
    for (int d = tid; d < DFF_; d += 256) Ps[d] = P[d] + span_b1[d];
    if (tid < E_) csh[tid] = cvec[b*E_ + tid];
    __syncthreads();
    int nsp = min(12, W_ - s);
    int nbase = rowstart_of(s);
    for (int i = 0; i < nsp; i++){
        int e = s + i;
        const float* Q = PQ + ((size_t)(bl*W_ + e))*1024 + DFF_;
        for (int d = tid; d < DFF_; d += 256){
            float h = Ps[d] + Q[d];
            hid[d] = h > 0.f ? h : 0.01f*h;
        }
        __syncthreads();
        {
            double acc = 0.0;
            int d0 = g*32;
            #pragma unroll
            for (int k = 0; k < 32; k++) acc += (double)hid[d0+k]*(double)Mreg[k];
            red[tid] = acc;
        }
        __syncthreads();
        if (tid < E_){
            double t = 0.0;
            for (int gg = 0; gg < 16; gg++) t += red[gg*16 + tid];
            float lg = (float)(t + (double)csh[tid]);
            size_t oi = ((size_t)b*N_ + nbase + i)*E_ + tid;
            logits[oi] = lg;
            outL[oi] = lg;
        }
        __syncthreads();
    }
}

// ---------------- per-span best candidate, packed with (s, len-1) in bits 48..60 ----------------
__global__ void k_spanbest(const float* __restrict__ logits,
                           const int* __restrict__ starts, const int* __restrict__ ends,
                           u64* __restrict__ candS){
    int idx = blockIdx.x*256 + threadIdx.x;      // over B_*N_
    if (idx >= B_*N_) return;
    int b = idx / N_; int n = idx - b*N_;
    const float* lg = logits + (size_t)b*NE_ + (size_t)n*16;
    u64 best = ~0ull;
    for (int e = 0; e < 16; e++){
        float prob = 1.0f/(1.0f + expf(-lg[e]));
        if (prob > 0.5f){
            u32 key24 = (~__float_as_uint(prob)) & 0xFFFFFFu;
            u64 pk = ((u64)key24 << 24) | (u64)(u32)(n*16 + e);
            best = best < pk ? best : pk;
        }
    }
    int s = starts[n], e2 = ends[n];
    int len = e2 - s + 1;
    u64 packed = best;
    if (best != ~0ull)
        packed = best | ((u64)(u32)s << 48) | ((u64)(u32)(len-1) << 57);
    candS[idx] = packed;
}

// ---------------- scalar-replay greedy decode (single wave, wave-uniform SALU loop) ----------------
// Stream read from LDS. Ballot once per 64-chunk; iterate tentative bits in a uniform
// scalar loop; coverage in 8 statically-indexed u64s. Identical decisions to reference.
__device__ __forceinline__ void decode_wave(const u64* sp, int n,
                                            float* __restrict__ outSel, int b){
    int lane = threadIdx.x & 63;
    u64 scov[8];
    #pragma unroll
    for (int k = 0; k < 8; k++) scov[k] = 0ull;
    int covcnt = 0;
    for (int base = 0; base < n; base += 64){
        int i = base + lane;
        bool has = i < n;
        u64 v = has ? sp[i] : ~0ull;
        int s   = (int)((v >> 48) & 0x1FFull);
        int len = (int)((v >> 57) & 0xFull) + 1;
        u32 c   = (u32)(v & 0xFFFFFFull);
        int w0 = s >> 6, sh0 = s & 63;
        int w1i = (w0 < 7) ? w0 + 1 : 7;
        u64 full = (1ull << len) - 1ull;
        u64 m0 = has ? (full << sh0) : 0ull;
        u64 m1 = (has && sh0 + len > 64) ? (full >> (64 - sh0)) : 0ull;
        u64 myc0 = 0ull, myc1 = 0ull;
        #pragma unroll
        for (int k = 0; k < 8; k++){
            if (w0  == k) myc0 = scov[k];
            if (w1i == k) myc1 = scov[k];
        }
        bool tent = has && (((myc0 & m0) | (myc1 & m1)) == 0ull);
        u64 bal = __ballot(tent);
        u32 vlo = (u32)v, vhi = (u32)(v >> 32);
        u64 acc = 0ull;
        while (bal){
            int j = (int)__builtin_ctzll(bal);
            bal &= bal - 1ull;
#if __has_builtin(__builtin_amdgcn_readlane)
            u32 jlo = (u32)__builtin_amdgcn_readlane((int)vlo, j);
            u32 jhi = (u32)__builtin_amdgcn_readlane((int)vhi, j);
#else
            u32 jlo = (u32)__shfl((int)vlo, j, 64);
            u32 jhi = (u32)__shfl((int)vhi, j, 64);
#endif
            u64 jv = ((u64)jhi << 32) | (u64)jlo;
            int js   = (int)((jv >> 48) & 0x1FFull);
            int jlen = (int)((jv >> 57) & 0xFull) + 1;
            int jw0 = js >> 6, jsh = js & 63;
            int jw1 = (jw0 < 7) ? jw0 + 1 : 7;
            u64 jfull = (1ull << jlen) - 1ull;
            u64 jm0 = jfull << jsh;
            u64 jm1 = (jsh + jlen > 64) ? (jfull >> (64 - jsh)) : 0ull;
            u64 c0 = 0ull, c1 = 0ull;
            #pragma unroll
            for (int k = 0; k < 8; k++){
                if (jw0 == k) c0 = scov[k];
                if (jw1 == k) c1 = scov[k];
            }
            bool ok = (((c0 & jm0) | (c1 & jm1)) == 0ull);
            u64 okm = ok ? ~0ull : 0ull;
            #pragma unroll
            for (int k = 0; k < 8; k++){
                u64 add = 0ull;
                if (jw0 == k) add |= jm0;
                if (jw1 == k) add |= jm1;   // jm1 nonzero only when crossing => jw1 != jw0
                scov[k] |= (add & okm);
            }
            covcnt += ok ? jlen : 0;
            acc |= (okm & (1ull << j));
        }
        if (((acc >> lane) & 1ull) != 0ull)
            outSel[(size_t)BNE_ + (size_t)b*NE_ + (size_t)c] = 1.0f;
        if (covcnt >= W_) break;
    }
}

// ---------------- fused tail, LDS-resident: DP -> compact -> rank-sort -> decode ----------------
// One block per batch. ~17 barriers total (was ~130). No global writes except outSel.
// Rank-sort: keys unique (low 48 bits = key24|flatid) -> rank via broadcast compare loop;
// ordering identical to the stable LSD radix it replaces.
__global__ __launch_bounds__(256) void k_tail(const u64* __restrict__ candS,
                                              float* __restrict__ outSel){
    __shared__ u64 cs[6016];          // 48,128 B: candidate table, then compacted+sorted
    __shared__ u64 Ma[512], Mb[512];  // 8,192 B: DP ping-pong
    __shared__ u32 wtot[4];
    __shared__ int nsh;
    int b = blockIdx.x; int tid = threadIdx.x;
    int lane = tid & 63, wave = tid >> 6;
    const u64* cSg = candS + (size_t)b*N_;

    // ---- load table -> LDS (coalesced) ----
    for (int i = tid; i < N_; i += 256) cs[i] = cSg[i];
    __syncthreads();

    // ---- Phase A: nested-dominance DP (11 rounds, LDS-resident) ----
    for (int s = tid; s < 512; s += 256)
        Ma[s] = (s < W_) ? (cs[rowstart_of(s)] & MAXK48) : MAXK48;
    __syncthreads();
    u64* Mcur = Ma; u64* Mnext = Mb;
    for (int l = 2; l <= 12; l++){
        #pragma unroll
        for (int q = 0; q < 2; q++){
            int s = tid + q*256;          // 0..511
            u64 key = MAXK48; int idx = -1;
            if (s + l <= W_){ idx = rowstart_of(s) + (l-1); key = cs[idx] & MAXK48; }
            u64 a = Mcur[s];
            u64 bb = (s + 1 < 512) ? Mcur[s+1] : MAXK48;
            u64 dom = a < bb ? a : bb;
            if (idx >= 0 && dom < key) cs[idx] = ~0ull;      // pruned
            Mnext[s] = dom < key ? dom : key;
        }
        __syncthreads();
        u64* t = Mcur; Mcur = Mnext; Mnext = t;
    }

    // ---- Phase B: in-place compaction (blocked, register-staged, 3 barriers) ----
    int base = tid*PT_;
    u64 vv[PT_];
    u32 flags = 0; int cnt = 0;
    #pragma unroll
    for (int k = 0; k < PT_; k++){
        int i = base + k;
        u64 v = (i < N_) ? cs[i] : ~0ull;
        vv[k] = v;
        if (v != ~0ull){ flags |= (1u << k); cnt++; }
    }
    u32 inc = (u32)cnt;
    for (int d = 1; d < 64; d <<= 1){ u32 o = (u32)__shfl_up((int)inc, d, 64); if (lane >= d) inc += o; }
    if (lane == 63) wtot[wave] = inc;
    __syncthreads();                       // fences all cs reads + wtot visible
    u32 woffs = 0;
    for (int w = 0; w < 4; w++) if (w < wave) woffs += wtot[w];
    u32 off = woffs + inc - (u32)cnt;      // exclusive offset (span order preserved)
    if (tid == 255) nsh = (int)(woffs + inc);
    #pragma unroll
    for (int k = 0; k < PT_; k++){
        if (flags & (1u << k)) cs[off++] = vv[k];
    }
    __syncthreads();                       // writes + nsh visible
    int n = nsh;
    if (tid < 4) cs[n + tid] = ~0ull;      // pad for paired reads
    __syncthreads();

    // ---- Phase C: rank-sort over low-48 keys (broadcast compare; conflict-free) ----
    u32 rr[PT_];
    #pragma unroll
    for (int k = 0; k < PT_; k++){ vv[k] = ~0ull; rr[k] = 0; }
    #pragma unroll
    for (int k = 0; k < PT_; k++){
        int i = tid + (k << 8);
        if (i < n){
            u64 v = cs[i];
            vv[k] = v;
            u64 ki = v & MAXK48;
            u32 r = 0;
            for (int j = 0; j < n; j += 2){
                u64 k0 = cs[j]   & MAXK48;   // same addr all lanes -> LDS broadcast
                u64 k1 = cs[j+1] & MAXK48;
                r += (k0 < ki) ? 1u : 0u;
                r += (k1 < ki) ? 1u : 0u;
            }
            rr[k] = r;
        }
    }
    __syncthreads();                       // all reads done before in-place scatter
    #pragma unroll
    for (int k = 0; k < PT_; k++){
        int i = tid + (k << 8);
        if (i < n) cs[rr[k]] = vv[k];      // unique keys -> rank is a permutation
    }
    __syncthreads();

    // ---- Phase D: decode on wave 0, LDS-resident stream ----
    if (wave == 0) decode_wave(cs, n, outSel, b);
}

extern "C" void kernel_launch(void* const* d_in, const int* in_sizes, int n_in,
                              void* d_out, int out_size, void* d_ws, size_t ws_size,
                              hipStream_t stream){
    const float* hs        = (const float*)d_in[0];
    const float* ent_w1    = (const float*)d_in[1];
    const float* ent_b1    = (const float*)d_in[2];
    const float* ent_w2    = (const float*)d_in[3];
    const float* ent_b2    = (const float*)d_in[4];
    const float* span_w1   = (const float*)d_in[5];
    const float* span_b1   = (const float*)d_in[6];
    const float* span_w2   = (const float*)d_in[7];
    const float* span_b2   = (const float*)d_in[8];
    const int*  text_mask  = (const int*)d_in[9];
    const int*  ent_mask   = (const int*)d_in[10];
    const int*  word_index = (const int*)d_in[11];
    float* out = (float*)d_out;

    // ---- workspace (~20.5 MB peak; candS overlays dead wemb) ----
    char* wsbase = (char*)d_ws; size_t off = 0;
    auto alloc = [&](size_t bytes)->void*{ void* p = wsbase + off; off = (off + bytes + 255) & ~(size_t)255; return p; };
    char*  region1 = (char*)alloc((size_t)B_*W_*H_*4);    // 12,386,304 B
    float* wemb   = (float*)region1;                       // phase 1
    u64*   candS  = (u64*)region1;                         // phase 2: 382,848 B
    int*   tok    = (int*)  alloc((size_t)B_*W_*4*4);
    int*   tokc   = (int*)  alloc((size_t)B_*W_*4);
    float* PQ     = (float*)alloc((size_t)2*W_*1024*4);    // 4,128,768 B (2 batches/pass)
    float* logits = (float*)alloc((size_t)BNE_*4);         // 3,062,784 B
    int*   entpos = (int*)  alloc((size_t)B_*E_*4);
    float* hidg   = (float*)alloc((size_t)B_*E_*DFF_*4);   // 262,144 B
    float* entvec = (float*)alloc((size_t)B_*E_*H_*4);
    float* Mmat   = (float*)alloc((size_t)B_*DFF_*E_*4);
    float* cvec   = (float*)alloc((size_t)B_*E_*4);
    int*   starts = (int*)  alloc((size_t)N_*4);
    int*   ends   = (int*)  alloc((size_t)N_*4);

    hipMemsetAsync((void*)(out + BNE_), 0, (size_t)BNE_*4, stream);   // selected := 0.0f
    hipMemsetAsync(tokc, 0, (size_t)B_*W_*4, stream);

    k_tables<<<8,64,0,stream>>>(starts, ends);
    k_toklist<<<(B_*L_+255)/256,256,0,stream>>>(text_mask, word_index, tok, tokc);
    k_toksort<<<(B_*W_+255)/256,256,0,stream>>>(tok, tokc);
    k_pool<<<(B_*W_*H_+255)/256,256,0,stream>>>(hs, tok, tokc, wemb);
    k_entpos<<<B_,64,0,stream>>>(ent_mask, entpos);
    k_ent1<<<B_*E_*2,256,0,stream>>>(hs, entpos, ent_w1, ent_b1, hidg);
    k_ent2<<<B_*E_*3,256,0,stream>>>(hidg, ent_w2, ent_b2, entvec);
    k_M<<<B_*32,256,0,stream>>>(span_w2, entvec, Mmat);
    k_c<<<(B_*E_+63)/64,64,0,stream>>>(span_b2, entvec, cvec);
    for (int b0 = 0; b0 < B_; b0 += 2){
        k_pq<<<256,256,0,stream>>>(wemb, span_w1, PQ, b0);
        k_logits<<<2*W_,256,0,stream>>>(PQ, Mmat, cvec, span_b1, logits, out, b0);
    }
    // wemb dead from here; region1 hosts candS
    k_spanbest<<<(B_*N_+255)/256,256,0,stream>>>(logits, starts, ends, candS);
    k_tail<<<B_,256,0,stream>>>(candS, out);
}

// Round 4
// 512.434 us; speedup vs baseline: 1.1744x; 1.1744x over previous
//
#include <hip/hip_runtime.h>
#include <hip/hip_bf16.h>
#include <stdint.h>

#define B_ 8
#define L_ 1024
#define H_ 768
#define E_ 16
#define W_ 504
#define DFF_ 512
#define N_ 5982
#define NE_ (N_*E_)    // 95712 candidates per batch
#define BNE_ (B_*NE_)  // 765696
#define MAXK48 0x0000FFFFFFFFFFFFull
#define PT_ 24         // per-thread elements in generic sort path: 24*256 = 6144 >= N_

typedef unsigned long long u64;
typedef unsigned int u32;

__device__ __forceinline__ int rowstart_of(int s){
    int s0 = W_ - 11; // 493
    if (s <= s0) return 12*s;
    int t = s - s0;
    return 12*s0 + t*11 - (t*(t-1))/2;
}

// ---------------- prolog: span tables + tokc zero (block 8), parallel entpos (blocks 0..7) ----
__global__ void k_prolog(const int* __restrict__ ent_mask, int* __restrict__ ent_pos,
                         int* __restrict__ starts, int* __restrict__ ends,
                         int* __restrict__ tokc){
    int blk = blockIdx.x; int tid = threadIdx.x;
    if (blk == 8){
        for (int s = tid; s < W_; s += 256){
            int rs = rowstart_of(s);
            int cnt = min(12, W_ - s);
            for (int i = 0; i < cnt; i++){ starts[rs+i] = s; ends[rs+i] = s+i; }
        }
        for (int i = tid; i < B_*W_; i += 256) tokc[i] = 0;
        return;
    }
    // stable compaction of entity positions (ascending), then non-entity fill.
    __shared__ u32 wt[4]; __shared__ u32 cbase;
    int b = blk;
    int lane = tid & 63, wave = tid >> 6;
    if (tid == 0) cbase = 0;
    __syncthreads();
    for (int base = 0; base < L_; base += 256){
        int l = base + tid;
        bool f = (ent_mask[b*L_ + l] == 1);
        u64 bal = __ballot(f);
        if (lane == 0) wt[wave] = (u32)__popcll(bal);
        __syncthreads();
        u32 pre = cbase;
        for (int w = 0; w < 4; w++) if (w < wave) pre += wt[w];
        if (f){
            u32 rank = pre + (u32)__popcll(bal & ((1ull<<lane)-1ull));
            if (rank < E_) ent_pos[b*E_ + rank] = l;
        }
        __syncthreads();
        if (tid == 0){ u32 r = cbase; for (int w = 0; w < 4; w++) r += wt[w]; cbase = r; }
        __syncthreads();
    }
    u32 totEnt = cbase;
    if (totEnt >= E_) return;                 // block-uniform
    for (int base = 0; base < L_; base += 256){
        int l = base + tid;
        bool f = (ent_mask[b*L_ + l] != 1);
        u64 bal = __ballot(f);
        if (lane == 0) wt[wave] = (u32)__popcll(bal);
        __syncthreads();
        u32 pre = cbase;
        for (int w = 0; w < 4; w++) if (w < wave) pre += wt[w];
        if (f){
            u32 rank = pre + (u32)__popcll(bal & ((1ull<<lane)-1ull));
            if (rank < E_) ent_pos[b*E_ + rank] = l;
        }
        __syncthreads();
        if (tid == 0){ u32 r = cbase; for (int w = 0; w < 4; w++) r += wt[w]; cbase = r; }
        __syncthreads();
    }
}

// ---------------- token lists: parallel build ----------------
__global__ void k_toklist(const int* __restrict__ tm, const int* __restrict__ wi,
                          int* __restrict__ tok, int* __restrict__ tokc){
    int i = blockIdx.x*256 + threadIdx.x;
    if (i >= B_*L_) return;
    int w = wi[i];
    if (tm[i] == 1 && w >= 0 && w < W_){
        int b = i / L_;
        int bw = b*W_ + w;
        int pos = atomicAdd(&tokc[bw], 1);
        if (pos < 4) tok[bw*4 + pos] = i - b*L_;
    }
}

// ---------------- fused per-word sort + mean pooling (one block per (b,w)) ----------------
__global__ void k_poolsort(const float* __restrict__ hs, const int* __restrict__ tok,
                           const int* __restrict__ tokc, float* __restrict__ wemb){
    __shared__ int stok[4]; __shared__ int scnt;
    int bw = blockIdx.x;                       // B_*W_
    int b = bw / W_;
    int tid = threadIdx.x;
    if (tid == 0){
        int c = tokc[bw]; int cc = min(c, 4);
        int v[4];
        for (int k = 0; k < cc; k++) v[k] = tok[bw*4 + k];
        for (int a = 1; a < cc; a++){ int x = v[a]; int j = a-1; while (j >= 0 && v[j] > x){ v[j+1] = v[j]; j--; } v[j+1] = x; }
        for (int k = 0; k < cc; k++) stok[k] = v[k];
        scnt = c;
    }
    __syncthreads();
    int c = scnt; int cc = min(c, 4);
    float denom = (float)max(c, 1);
    for (int h = tid; h < H_; h += 256){
        double s = 0.0;
        for (int k = 0; k < cc; k++)
            s += (double)hs[((size_t)(b*L_ + stok[k]))*H_ + h];
        wemb[(size_t)bw*H_ + h] = (float)(s / (double)denom);
    }
}

// ---------------- fused entity MLP (layer1 -> LDS -> layer2), one block per be ----------------
// Accumulation orders identical to the previous split kernels -> bit-identical ent_vec.
__global__ void k_ent(const float* __restrict__ hs, const int* __restrict__ ent_pos,
                      const float* __restrict__ w1, const float* __restrict__ b1,
                      const float* __restrict__ w2, const float* __restrict__ b2,
                      float* __restrict__ ent_vec){
    __shared__ float x[H_];
    __shared__ float hid[DFF_];
    int be = blockIdx.x;                       // 128
    int b = be >> 4;
    int tid = threadIdx.x;
    int pos = ent_pos[be];
    const float* xp = hs + ((size_t)b*L_ + pos)*H_;
    for (int j = tid; j < H_; j += 256) x[j] = xp[j];
    __syncthreads();
    #pragma unroll
    for (int q = 0; q < 2; q++){
        int d = q*256 + tid;
        float a0=0.f,a1=0.f,a2=0.f,a3=0.f;
        const float* wp = w1 + d;
        #pragma unroll 4
        for (int h = 0; h < H_; h += 4){
            a0 += x[h+0]*wp[(size_t)(h+0)*DFF_];
            a1 += x[h+1]*wp[(size_t)(h+1)*DFF_];
            a2 += x[h+2]*wp[(size_t)(h+2)*DFF_];
            a3 += x[h+3]*wp[(size_t)(h+3)*DFF_];
        }
        float acc = ((a0+a1)+(a2+a3)) + b1[d];
        hid[d] = acc > 0.f ? acc : 0.01f*acc;
    }
    __syncthreads();
    #pragma unroll
    for (int q = 0; q < 3; q++){
        int j = q*256 + tid;
        float a0=0.f,a1=0.f,a2=0.f,a3=0.f;
        const float* wp = w2 + j;
        #pragma unroll 4
        for (int d = 0; d < DFF_; d += 4){
            a0 += hid[d+0]*wp[(size_t)(d+0)*H_];
            a1 += hid[d+1]*wp[(size_t)(d+1)*H_];
            a2 += hid[d+2]*wp[(size_t)(d+2)*H_];
            a3 += hid[d+3]*wp[(size_t)(d+3)*H_];
        }
        ent_vec[(size_t)be*H_ + j] = ((a0+a1)+(a2+a3)) + b2[j];
    }
}

// ---------------- fused M + c: blocks 0..255 = M, block 256 = c (fp64, decode-critical) ------
__global__ void k_Mc(const float* __restrict__ span_w2, const float* __restrict__ span_b2,
                     const float* __restrict__ ent_vec, float* __restrict__ M,
                     float* __restrict__ cvec){
    int blk = blockIdx.x;
    if (blk == 256){
        int i = threadIdx.x;
        if (i < B_*E_){
            const float* ev = ent_vec + (size_t)i*H_;
            double acc = 0.0;
            for (int h = 0; h < H_; h++) acc += (double)span_b2[h]*(double)ev[h];
            cvec[i] = (float)acc;
        }
        return;
    }
    int b = blk/32; int dbase = (blk%32)*16;
    int tid = threadIdx.x; int d = dbase + (tid>>4); int e = tid&15;
    const float* ev = ent_vec + ((size_t)b*E_ + e)*H_;
    const float* wr = span_w2 + (size_t)d*H_;
    double p0=0.0, p1=0.0;
    for (int h = 0; h < H_; h += 2){
        p0 += (double)wr[h]*(double)ev[h];
        p1 += (double)wr[h+1]*(double)ev[h+1];
    }
    M[((size_t)b*DFF_ + d)*E_ + e] = (float)(p0+p1);
}

// ---------------- P/Q projection: tiled fp32 GEMM, 64x64 tiles, 4 batches per pass ----------
//   C[2016 x 1024] = A[2016 x 768] @ Bmat[768 x 1024]
__global__ void k_pq(const float* __restrict__ wemb, const float* __restrict__ w1,
                     float* __restrict__ PQ, int b0){
    __shared__ float As[16][68];
    __shared__ float Bs[16][68];
    int bx = blockIdx.x & 15;      // col tile
    int by = blockIdx.x >> 4;      // row tile (0..31)
    int tid = threadIdx.x;
    int tm = tid >> 4, tn = tid & 15;
    const float* A0 = wemb + (size_t)b0*W_*H_;
    int colbase = bx*64;
    const float* Bbase = (colbase < DFF_) ? w1 : (w1 + (size_t)H_*DFF_);
    int bcol0 = (colbase < DFF_) ? colbase : (colbase - DFF_);
    float acc[4][4] = {{0.f}};
    int ar = tid >> 2, akq = tid & 3;
    int bkk = tid >> 4, bcq = tid & 15;
    const int ROWS = 4*W_;         // 2016
    for (int k0 = 0; k0 < H_; k0 += 16){
        {
            int gr = by*64 + ar;
            float4 av;
            if (gr < ROWS) av = *(const float4*)(A0 + (size_t)gr*H_ + k0 + akq*4);
            else av = make_float4(0.f,0.f,0.f,0.f);
            As[akq*4+0][ar] = av.x; As[akq*4+1][ar] = av.y;
            As[akq*4+2][ar] = av.z; As[akq*4+3][ar] = av.w;
        }
        {
            float4 bv = *(const float4*)(Bbase + (size_t)(k0+bkk)*DFF_ + bcol0 + bcq*4);
            Bs[bkk][bcq*4+0] = bv.x; Bs[bkk][bcq*4+1] = bv.y;
            Bs[bkk][bcq*4+2] = bv.z; Bs[bkk][bcq*4+3] = bv.w;
        }
        __syncthreads();
        #pragma unroll
        for (int kk = 0; kk < 16; kk++){
            float4 a = *(const float4*)&As[kk][tm*4];
            float4 bv = *(const float4*)&Bs[kk][tn*4];
            acc[0][0] += a.x*bv.x; acc[0][1] += a.x*bv.y; acc[0][2] += a.x*bv.z; acc[0][3] += a.x*bv.w;
            acc[1][0] += a.y*bv.x; acc[1][1] += a.y*bv.y; acc[1][2] += a.y*bv.z; acc[1][3] += a.y*bv.w;
            acc[2][0] += a.z*bv.x; acc[2][1] += a.z*bv.y; acc[2][2] += a.z*bv.z; acc[2][3] += a.z*bv.w;
            acc[3][0] += a.w*bv.x; acc[3][1] += a.w*bv.y; acc[3][2] += a.w*bv.z; acc[3][3] += a.w*bv.w;
        }
        __syncthreads();
    }
    #pragma unroll
    for (int r = 0; r < 4; r++){
        int gr = by*64 + tm*4 + r;
        if (gr < ROWS){
            float4 ov = make_float4(acc[r][0], acc[r][1], acc[r][2], acc[r][3]);
            *(float4*)(PQ + (size_t)gr*1024 + colbase + tn*4) = ov;
        }
    }
}

// ---------------- logits: one block per (bl, s); wave-shuffle fp64 pre-reduce ----------------
__global__ void k_logits(const float* __restrict__ PQ, const float* __restrict__ Mmat,
                         const float* __restrict__ cvec, const float* __restrict__ span_b1,
                         float* __restrict__ logits, float* __restrict__ outL, int b0){
    __shared__ float Ps[DFF_];
    __shared__ float hid[DFF_];
    __shared__ double redw[64];
    __shared__ float csh[E_];
    int blk = blockIdx.x;            // 4*W_ blocks
    int bl = blk / W_; int s = blk - bl*W_;
    int b = b0 + bl;
    int tid = threadIdx.x;
    int lane = tid & 63, wave = tid >> 6;
    int ee = tid & 15; int g = tid >> 4;   // 16 groups x 32 d
    float Mreg[32];
    {
        const float* Mp = Mmat + (size_t)b*DFF_*E_ + (size_t)(g*32)*E_ + ee;
        #pragma unroll
        for (int i = 0; i < 32; i++) Mreg[i] = Mp[(size_t)i*E_];
    }
    const float* P = PQ + ((size_t)(bl*W_ + s))*1024;
    for (int d = tid; d < DFF_; d += 256) Ps[d] = P[d] + span_b1[d];
    if (tid < E_) csh[tid] = cvec[b*E_ + tid];
    __syncthreads();
    int nsp = min(12, W_ - s);
    int nbase = rowstart_of(s);
    for (int i = 0; i < nsp; i++){
        int e = s + i;
        const float* Q = PQ + ((size_t)(bl*W_ + e))*1024 + DFF_;
        for (int d = tid; d < DFF_; d += 256){
            float h = Ps[d] + Q[d];
            hid[d] = h > 0.f ? h : 0.01f*h;
        }
        __syncthreads();
        {
            double acc = 0.0;
            int d0 = g*32;
            #pragma unroll
            for (int k = 0; k < 32; k++) acc += (double)hid[d0+k]*(double)Mreg[k];
            // wave pre-reduce over the wave's 4 g-groups (same ee)
            double t = acc + __shfl_down(acc, 32, 64);
            t = t + __shfl_down(t, 16, 64);
            if (lane < 16) redw[wave*16 + lane] = t;
        }
        __syncthreads();
        if (tid < E_){
            double t = ((redw[tid] + redw[16+tid]) + (redw[32+tid] + redw[48+tid]))
                     + (double)csh[tid];
            float lg = (float)t;
            size_t oi = ((size_t)b*N_ + nbase + i)*E_ + tid;
            logits[oi] = lg;
            outL[oi] = lg;
        }
        __syncthreads();
    }
}

// ---------------- per-span best candidate + selected-region zeroing ----------------
__global__ void k_spanbest(const float* __restrict__ logits,
                           const int* __restrict__ starts, const int* __restrict__ ends,
                           u64* __restrict__ candS, float* __restrict__ outSel){
    int idx = blockIdx.x*256 + threadIdx.x;      // over B_*N_
    if (idx >= B_*N_) return;
    int b = idx / N_; int n = idx - b*N_;
    const float* lg = logits + (size_t)b*NE_ + (size_t)n*16;
    u64 best = ~0ull;
    for (int e = 0; e < 16; e++){
        float prob = 1.0f/(1.0f + expf(-lg[e]));
        if (prob > 0.5f){
            u32 key24 = (~__float_as_uint(prob)) & 0xFFFFFFu;
            u64 pk = ((u64)key24 << 24) | (u64)(u32)(n*16 + e);
            best = best < pk ? best : pk;
        }
    }
    int s = starts[n], e2 = ends[n];
    int len = e2 - s + 1;
    u64 packed = best;
    if (best != ~0ull)
        packed = best | ((u64)(u32)s << 48) | ((u64)(u32)(len-1) << 57);
    candS[idx] = packed;
    // zero the selected region (decode sets 1.0s later)
    float* selp = outSel + (size_t)BNE_ + (size_t)b*NE_ + (size_t)n*16;
    float4 z = make_float4(0.f,0.f,0.f,0.f);
    *(float4*)(selp+0)  = z; *(float4*)(selp+4)  = z;
    *(float4*)(selp+8)  = z; *(float4*)(selp+12) = z;
}

// ---------------- scalar-replay greedy decode (single wave, wave-uniform SALU loop) ----------
__device__ __forceinline__ void decode_wave(const u64* sp, int n,
                                            float* __restrict__ outSel, int b){
    int lane = threadIdx.x & 63;
    u64 scov[8];
    #pragma unroll
    for (int k = 0; k < 8; k++) scov[k] = 0ull;
    int covcnt = 0;
    for (int base = 0; base < n; base += 64){
        int i = base + lane;
        bool has = i < n;
        u64 v = has ? sp[i] : ~0ull;
        int s   = (int)((v >> 48) & 0x1FFull);
        int len = (int)((v >> 57) & 0xFull) + 1;
        u32 c   = (u32)(v & 0xFFFFFFull);
        int w0 = s >> 6, sh0 = s & 63;
        int w1i = (w0 < 7) ? w0 + 1 : 7;
        u64 full = (1ull << len) - 1ull;
        u64 m0 = has ? (full << sh0) : 0ull;
        u64 m1 = (has && sh0 + len > 64) ? (full >> (64 - sh0)) : 0ull;
        u64 myc0 = 0ull, myc1 = 0ull;
        #pragma unroll
        for (int k = 0; k < 8; k++){
            if (w0  == k) myc0 = scov[k];
            if (w1i == k) myc1 = scov[k];
        }
        bool tent = has && (((myc0 & m0) | (myc1 & m1)) == 0ull);
        u64 bal = __ballot(tent);
        u32 vlo = (u32)v, vhi = (u32)(v >> 32);
        u64 acc = 0ull;
        while (bal){
            int j = (int)__builtin_ctzll(bal);
            bal &= bal - 1ull;
#if __has_builtin(__builtin_amdgcn_readlane)
            u32 jlo = (u32)__builtin_amdgcn_readlane((int)vlo, j);
            u32 jhi = (u32)__builtin_amdgcn_readlane((int)vhi, j);
#else
            u32 jlo = (u32)__shfl((int)vlo, j, 64);
            u32 jhi = (u32)__shfl((int)vhi, j, 64);
#endif
            u64 jv = ((u64)jhi << 32) | (u64)jlo;
            int js   = (int)((jv >> 48) & 0x1FFull);
            int jlen = (int)((jv >> 57) & 0xFull) + 1;
            int jw0 = js >> 6, jsh = js & 63;
            int jw1 = (jw0 < 7) ? jw0 + 1 : 7;
            u64 jfull = (1ull << jlen) - 1ull;
            u64 jm0 = jfull << jsh;
            u64 jm1 = (jsh + jlen > 64) ? (jfull >> (64 - jsh)) : 0ull;
            u64 c0 = 0ull, c1 = 0ull;
            #pragma unroll
            for (int k = 0; k < 8; k++){
                if (jw0 == k) c0 = scov[k];
                if (jw1 == k) c1 = scov[k];
            }
            bool ok = (((c0 & jm0) | (c1 & jm1)) == 0ull);
            u64 okm = ok ? ~0ull : 0ull;
            #pragma unroll
            for (int k = 0; k < 8; k++){
                u64 add = 0ull;
                if (jw0 == k) add |= jm0;
                if (jw1 == k) add |= jm1;
                scov[k] |= (add & okm);
            }
            covcnt += ok ? jlen : 0;
            acc |= (okm & (1ull << j));
        }
        if (((acc >> lane) & 1ull) != 0ull)
            outSel[(size_t)BNE_ + (size_t)b*NE_ + (size_t)c] = 1.0f;
        if (covcnt >= W_) break;
    }
}

// ---------------- fused tail, LDS-resident: DP -> compact -> rank-sort -> decode -------------
// Sort fast path (n<=1024, always in practice): 4 owned elements in named registers; one
// shared j-loop with 8 ds_read_b64 in flight per waitcnt (latency amortized 8x).
__global__ __launch_bounds__(256) void k_tail(const u64* __restrict__ candS,
                                              float* __restrict__ outSel){
    __shared__ u64 cs[6032];          // candidate table, then compacted+sorted (+pad 8)
    __shared__ u64 Ma[512], Mb[512];  // DP ping-pong
    __shared__ u32 wtot[4];
    __shared__ int nsh;
    int b = blockIdx.x; int tid = threadIdx.x;
    int lane = tid & 63, wave = tid >> 6;
    const u64* cSg = candS + (size_t)b*N_;

    // ---- load table -> LDS (coalesced, independent loads pipeline) ----
    for (int i = tid; i < N_; i += 256) cs[i] = cSg[i];
    __syncthreads();

    // ---- Phase A: nested-dominance DP (11 rounds) ----
    for (int s = tid; s < 512; s += 256)
        Ma[s] = (s < W_) ? (cs[rowstart_of(s)] & MAXK48) : MAXK48;
    __syncthreads();
    u64* Mcur = Ma; u64* Mnext = Mb;
    for (int l = 2; l <= 12; l++){
        #pragma unroll
        for (int q = 0; q < 2; q++){
            int s = tid + q*256;          // 0..511
            u64 key = MAXK48; int idx = -1;
            if (s + l <= W_){ idx = rowstart_of(s) + (l-1); key = cs[idx] & MAXK48; }
            u64 a = Mcur[s];
            u64 bb = (s + 1 < 512) ? Mcur[s+1] : MAXK48;
            u64 dom = a < bb ? a : bb;
            if (idx >= 0 && dom < key) cs[idx] = ~0ull;      // pruned
            Mnext[s] = dom < key ? dom : key;
        }
        __syncthreads();
        u64* t = Mcur; Mcur = Mnext; Mnext = t;
    }

    // ---- Phase B: in-place compaction (blocked, register-staged) ----
    {
        int base = tid*PT_;
        u64 vv[PT_];
        u32 flags = 0; int cnt = 0;
        #pragma unroll
        for (int k = 0; k < PT_; k++){
            int i = base + k;
            u64 v = (i < N_) ? cs[i] : ~0ull;
            vv[k] = v;
            if (v != ~0ull){ flags |= (1u << k); cnt++; }
        }
        u32 inc = (u32)cnt;
        for (int d = 1; d < 64; d <<= 1){ u32 o = (u32)__shfl_up((int)inc, d, 64); if (lane >= d) inc += o; }
        if (lane == 63) wtot[wave] = inc;
        __syncthreads();
        u32 woffs = 0;
        for (int w = 0; w < 4; w++) if (w < wave) woffs += wtot[w];
        u32 off = woffs + inc - (u32)cnt;
        if (tid == 255) nsh = (int)(woffs + inc);
        #pragma unroll
        for (int k = 0; k < PT_; k++){
            if (flags & (1u << k)) cs[off++] = vv[k];
        }
    }
    __syncthreads();
    int n = nsh;
    if (tid < 8) cs[n + tid] = ~0ull;      // pad for 8-wide batched reads
    __syncthreads();

    // ---- Phase C: rank-sort over low-48 keys ----
    if (n <= 1024){
        // fast path: <=4 owned elements, named registers, shared 8-wide load batches
        u64 v0=~0ull, v1=~0ull, v2=~0ull, v3=~0ull;
        u64 k0=0, k1=0, k2=0, k3=0;        // sentinel 0 -> rank stays 0 (unused)
        if (tid       < n){ v0 = cs[tid];       k0 = v0 & MAXK48; }
        if (tid + 256 < n){ v1 = cs[tid + 256]; k1 = v1 & MAXK48; }
        if (tid + 512 < n){ v2 = cs[tid + 512]; k2 = v2 & MAXK48; }
        if (tid + 768 < n){ v3 = cs[tid + 768]; k3 = v3 & MAXK48; }
        u32 r0=0, r1=0, r2=0, r3=0;
        for (int j = 0; j < n; j += 8){
            u64 c0 = cs[j+0] & MAXK48, c1 = cs[j+1] & MAXK48;
            u64 c2 = cs[j+2] & MAXK48, c3 = cs[j+3] & MAXK48;
            u64 c4 = cs[j+4] & MAXK48, c5 = cs[j+5] & MAXK48;
            u64 c6 = cs[j+6] & MAXK48, c7 = cs[j+7] & MAXK48;
            r0 += (u32)(c0<k0) + (u32)(c1<k0) + (u32)(c2<k0) + (u32)(c3<k0)
                + (u32)(c4<k0) + (u32)(c5<k0) + (u32)(c6<k0) + (u32)(c7<k0);
            r1 += (u32)(c0<k1) + (u32)(c1<k1) + (u32)(c2<k1) + (u32)(c3<k1)
                + (u32)(c4<k1) + (u32)(c5<k1) + (u32)(c6<k1) + (u32)(c7<k1);
            r2 += (u32)(c0<k2) + (u32)(c1<k2) + (u32)(c2<k2) + (u32)(c3<k2)
                + (u32)(c4<k2) + (u32)(c5<k2) + (u32)(c6<k2) + (u32)(c7<k2);
            r3 += (u32)(c0<k3) + (u32)(c1<k3) + (u32)(c2<k3) + (u32)(c3<k3)
                + (u32)(c4<k3) + (u32)(c5<k3) + (u32)(c6<k3) + (u32)(c7<k3);
        }
        __syncthreads();
        if (tid       < n) cs[r0] = v0;
        if (tid + 256 < n) cs[r1] = v1;
        if (tid + 512 < n) cs[r2] = v2;
        if (tid + 768 < n) cs[r3] = v3;
        __syncthreads();
    } else {
        // generic path (never expected; kept for correctness)
        u64 vv[PT_]; u32 rr[PT_];
        #pragma unroll
        for (int k = 0; k < PT_; k++){ vv[k] = ~0ull; rr[k] = 0; }
        #pragma unroll
        for (int k = 0; k < PT_; k++){
            int i = tid + (k << 8);
            if (i < n){
                u64 v = cs[i];
                vv[k] = v;
                u64 ki = v & MAXK48;
                u32 r = 0;
                for (int j = 0; j < n; j += 8){
                    u64 c0 = cs[j+0]&MAXK48, c1 = cs[j+1]&MAXK48;
                    u64 c2 = cs[j+2]&MAXK48, c3 = cs[j+3]&MAXK48;
                    u64 c4 = cs[j+4]&MAXK48, c5 = cs[j+5]&MAXK48;
                    u64 c6 = cs[j+6]&MAXK48, c7 = cs[j+7]&MAXK48;
                    r += (u32)(c0<ki) + (u32)(c1<ki) + (u32)(c2<ki) + (u32)(c3<ki)
                       + (u32)(c4<ki) + (u32)(c5<ki) + (u32)(c6<ki) + (u32)(c7<ki);
                }
                rr[k] = r;
            }
        }
        __syncthreads();
        #pragma unroll
        for (int k = 0; k < PT_; k++){
            int i = tid + (k << 8);
            if (i < n) cs[rr[k]] = vv[k];
        }
        __syncthreads();
    }

    // ---- Phase D: decode on wave 0, LDS-resident stream ----
    if (wave == 0) decode_wave(cs, n, outSel, b);
}

extern "C" void kernel_launch(void* const* d_in, const int* in_sizes, int n_in,
                              void* d_out, int out_size, void* d_ws, size_t ws_size,
                              hipStream_t stream){
    const float* hs        = (const float*)d_in[0];
    const float* ent_w1    = (const float*)d_in[1];
    const float* ent_b1    = (const float*)d_in[2];
    const float* ent_w2    = (const float*)d_in[3];
    const float* ent_b2    = (const float*)d_in[4];
    const float* span_w1   = (const float*)d_in[5];
    const float* span_b1   = (const float*)d_in[6];
    const float* span_w2   = (const float*)d_in[7];
    const float* span_b2   = (const float*)d_in[8];
    const int*  text_mask  = (const int*)d_in[9];
    const int*  ent_mask   = (const int*)d_in[10];
    const int*  word_index = (const int*)d_in[11];
    float* out = (float*)d_out;

    // ---- workspace (~24.5 MB peak; candS overlays dead wemb) ----
    char* wsbase = (char*)d_ws; size_t off = 0;
    auto alloc = [&](size_t bytes)->void*{ void* p = wsbase + off; off = (off + bytes + 255) & ~(size_t)255; return p; };
    char*  region1 = (char*)alloc((size_t)B_*W_*H_*4);    // 12,386,304 B
    float* wemb   = (float*)region1;                       // phase 1
    u64*   candS  = (u64*)region1;                         // phase 2: 382,848 B
    int*   tok    = (int*)  alloc((size_t)B_*W_*4*4);
    int*   tokc   = (int*)  alloc((size_t)B_*W_*4);
    float* PQ     = (float*)alloc((size_t)4*W_*1024*4);    // 8,257,536 B (4 batches/pass)
    float* logits = (float*)alloc((size_t)BNE_*4);         // 3,062,784 B
    int*   entpos = (int*)  alloc((size_t)B_*E_*4);
    float* entvec = (float*)alloc((size_t)B_*E_*H_*4);
    float* Mmat   = (float*)alloc((size_t)B_*DFF_*E_*4);
    float* cvec   = (float*)alloc((size_t)B_*E_*4);
    int*   starts = (int*)  alloc((size_t)N_*4);
    int*   ends   = (int*)  alloc((size_t)N_*4);

    k_prolog<<<9,256,0,stream>>>(ent_mask, entpos, starts, ends, tokc);
    k_toklist<<<(B_*L_+255)/256,256,0,stream>>>(text_mask, word_index, tok, tokc);
    k_poolsort<<<B_*W_,256,0,stream>>>(hs, tok, tokc, wemb);
    k_ent<<<B_*E_,256,0,stream>>>(hs, entpos, ent_w1, ent_b1, ent_w2, ent_b2, entvec);
    k_Mc<<<257,256,0,stream>>>(span_w2, span_b2, entvec, Mmat, cvec);
    for (int b0 = 0; b0 < B_; b0 += 4){
        k_pq<<<512,256,0,stream>>>(wemb, span_w1, PQ, b0);
        k_logits<<<4*W_,256,0,stream>>>(PQ, Mmat, cvec, span_b1, logits, out, b0);
    }
    // wemb dead from here; region1 hosts candS
    k_spanbest<<<(B_*N_+255)/256,256,0,stream>>>(logits, starts, ends, candS, out);
    k_tail<<<B_,256,0,stream>>>(candS, out);
}

// Round 6
// 487.555 us; speedup vs baseline: 1.2343x; 1.0510x over previous
//
#include <hip/hip_runtime.h>
#include <hip/hip_bf16.h>
#include <stdint.h>

#define B_ 8
#define L_ 1024
#define H_ 768
#define E_ 16
#define W_ 504
#define DFF_ 512
#define N_ 5982
#define NE_ (N_*E_)    // 95712 candidates per batch
#define BNE_ (B_*NE_)  // 765696
#define MAXK48 0x0000FFFFFFFFFFFFull
#define PT_ 24         // per-thread elements in generic sort path: 24*256 = 6144 >= N_

typedef unsigned long long u64;
typedef unsigned int u32;

__device__ __forceinline__ int rowstart_of(int s){
    int s0 = W_ - 11; // 493
    if (s <= s0) return 12*s;
    int t = s - s0;
    return 12*s0 + t*11 - (t*(t-1))/2;
}

__device__ __forceinline__ u64 shflup_u64(u64 x, int d){
    u32 lo = (u32)__shfl_up((int)(u32)x, d, 64);
    u32 hi = (u32)__shfl_up((int)(u32)(x >> 32), d, 64);
    return ((u64)hi << 32) | (u64)lo;
}
__device__ __forceinline__ u64 shflxor_u64(u64 x, int m){
    u32 lo = (u32)__shfl_xor((int)(u32)x, m, 64);
    u32 hi = (u32)__shfl_xor((int)(u32)(x >> 32), m, 64);
    return ((u64)hi << 32) | (u64)lo;
}

// ---------------- prolog: span tables + tokc zero (block 8), parallel entpos (blocks 0..7) ----
__global__ void k_prolog(const int* __restrict__ ent_mask, int* __restrict__ ent_pos,
                         int* __restrict__ starts, int* __restrict__ ends,
                         int* __restrict__ tokc){
    int blk = blockIdx.x; int tid = threadIdx.x;
    if (blk == 8){
        for (int s = tid; s < W_; s += 256){
            int rs = rowstart_of(s);
            int cnt = min(12, W_ - s);
            for (int i = 0; i < cnt; i++){ starts[rs+i] = s; ends[rs+i] = s+i; }
        }
        for (int i = tid; i < B_*W_; i += 256) tokc[i] = 0;
        return;
    }
    __shared__ u32 wt[4]; __shared__ u32 cbase;
    int b = blk;
    int lane = tid & 63, wave = tid >> 6;
    if (tid == 0) cbase = 0;
    __syncthreads();
    for (int base = 0; base < L_; base += 256){
        int l = base + tid;
        bool f = (ent_mask[b*L_ + l] == 1);
        u64 bal = __ballot(f);
        if (lane == 0) wt[wave] = (u32)__popcll(bal);
        __syncthreads();
        u32 pre = cbase;
        for (int w = 0; w < 4; w++) if (w < wave) pre += wt[w];
        if (f){
            u32 rank = pre + (u32)__popcll(bal & ((1ull<<lane)-1ull));
            if (rank < E_) ent_pos[b*E_ + rank] = l;
        }
        __syncthreads();
        if (tid == 0){ u32 r = cbase; for (int w = 0; w < 4; w++) r += wt[w]; cbase = r; }
        __syncthreads();
    }
    u32 totEnt = cbase;
    if (totEnt >= E_) return;                 // block-uniform
    for (int base = 0; base < L_; base += 256){
        int l = base + tid;
        bool f = (ent_mask[b*L_ + l] != 1);
        u64 bal = __ballot(f);
        if (lane == 0) wt[wave] = (u32)__popcll(bal);
        __syncthreads();
        u32 pre = cbase;
        for (int w = 0; w < 4; w++) if (w < wave) pre += wt[w];
        if (f){
            u32 rank = pre + (u32)__popcll(bal & ((1ull<<lane)-1ull));
            if (rank < E_) ent_pos[b*E_ + rank] = l;
        }
        __syncthreads();
        if (tid == 0){ u32 r = cbase; for (int w = 0; w < 4; w++) r += wt[w]; cbase = r; }
        __syncthreads();
    }
}

// ---------------- token lists: parallel build ----------------
__global__ void k_toklist(const int* __restrict__ tm, const int* __restrict__ wi,
                          int* __restrict__ tok, int* __restrict__ tokc){
    int i = blockIdx.x*256 + threadIdx.x;
    if (i >= B_*L_) return;
    int w = wi[i];
    if (tm[i] == 1 && w >= 0 && w < W_){
        int b = i / L_;
        int bw = b*W_ + w;
        int pos = atomicAdd(&tokc[bw], 1);
        if (pos < 4) tok[bw*4 + pos] = i - b*L_;
    }
}

// ---------------- fused per-word sort + mean pooling (one block per (b,w)) ----------------
__global__ void k_poolsort(const float* __restrict__ hs, const int* __restrict__ tok,
                           const int* __restrict__ tokc, float* __restrict__ wemb){
    __shared__ int stok[4]; __shared__ int scnt;
    int bw = blockIdx.x;                       // B_*W_
    int b = bw / W_;
    int tid = threadIdx.x;
    if (tid == 0){
        int c = tokc[bw]; int cc = min(c, 4);
        int v[4];
        for (int k = 0; k < cc; k++) v[k] = tok[bw*4 + k];
        for (int a = 1; a < cc; a++){ int x = v[a]; int j = a-1; while (j >= 0 && v[j] > x){ v[j+1] = v[j]; j--; } v[j+1] = x; }
        for (int k = 0; k < cc; k++) stok[k] = v[k];
        scnt = c;
    }
    __syncthreads();
    int c = scnt; int cc = min(c, 4);
    float denom = (float)max(c, 1);
    for (int h = tid; h < H_; h += 256){
        double s = 0.0;
        for (int k = 0; k < cc; k++)
            s += (double)hs[((size_t)(b*L_ + stok[k]))*H_ + h];
        wemb[(size_t)bw*H_ + h] = (float)(s / (double)denom);
    }
}

// ---------------- fused entity MLP (layer1 -> LDS -> layer2), one block per be ----------------
__global__ void k_ent(const float* __restrict__ hs, const int* __restrict__ ent_pos,
                      const float* __restrict__ w1, const float* __restrict__ b1,
                      const float* __restrict__ w2, const float* __restrict__ b2,
                      float* __restrict__ ent_vec){
    __shared__ float x[H_];
    __shared__ float hid[DFF_];
    int be = blockIdx.x;                       // 128
    int b = be >> 4;
    int tid = threadIdx.x;
    int pos = ent_pos[be];
    const float* xp = hs + ((size_t)b*L_ + pos)*H_;
    for (int j = tid; j < H_; j += 256) x[j] = xp[j];
    __syncthreads();
    #pragma unroll
    for (int q = 0; q < 2; q++){
        int d = q*256 + tid;
        float a0=0.f,a1=0.f,a2=0.f,a3=0.f;
        const float* wp = w1 + d;
        #pragma unroll 4
        for (int h = 0; h < H_; h += 4){
            a0 += x[h+0]*wp[(size_t)(h+0)*DFF_];
            a1 += x[h+1]*wp[(size_t)(h+1)*DFF_];
            a2 += x[h+2]*wp[(size_t)(h+2)*DFF_];
            a3 += x[h+3]*wp[(size_t)(h+3)*DFF_];
        }
        float acc = ((a0+a1)+(a2+a3)) + b1[d];
        hid[d] = acc > 0.f ? acc : 0.01f*acc;
    }
    __syncthreads();
    #pragma unroll
    for (int q = 0; q < 3; q++){
        int j = q*256 + tid;
        float a0=0.f,a1=0.f,a2=0.f,a3=0.f;
        const float* wp = w2 + j;
        #pragma unroll 4
        for (int d = 0; d < DFF_; d += 4){
            a0 += hid[d+0]*wp[(size_t)(d+0)*H_];
            a1 += hid[d+1]*wp[(size_t)(d+1)*H_];
            a2 += hid[d+2]*wp[(size_t)(d+2)*H_];
            a3 += hid[d+3]*wp[(size_t)(d+3)*H_];
        }
        ent_vec[(size_t)be*H_ + j] = ((a0+a1)+(a2+a3)) + b2[j];
    }
}

// ---------------- fused M + c: blocks 0..255 = M, block 256 = c (fp64, decode-critical) ------
__global__ void k_Mc(const float* __restrict__ span_w2, const float* __restrict__ span_b2,
                     const float* __restrict__ ent_vec, float* __restrict__ M,
                     float* __restrict__ cvec){
    int blk = blockIdx.x;
    if (blk == 256){
        int i = threadIdx.x;
        if (i < B_*E_){
            const float* ev = ent_vec + (size_t)i*H_;
            double acc = 0.0;
            for (int h = 0; h < H_; h++) acc += (double)span_b2[h]*(double)ev[h];
            cvec[i] = (float)acc;
        }
        return;
    }
    int b = blk/32; int dbase = (blk%32)*16;
    int tid = threadIdx.x; int d = dbase + (tid>>4); int e = tid&15;
    const float* ev = ent_vec + ((size_t)b*E_ + e)*H_;
    const float* wr = span_w2 + (size_t)d*H_;
    double p0=0.0, p1=0.0;
    for (int h = 0; h < H_; h += 2){
        p0 += (double)wr[h]*(double)ev[h];
        p1 += (double)wr[h+1]*(double)ev[h+1];
    }
    M[((size_t)b*DFF_ + d)*E_ + e] = (float)(p0+p1);
}

// ---------------- P/Q projection: tiled fp32 GEMM, 64x64 tiles, 4 batches per pass ----------
__global__ void k_pq(const float* __restrict__ wemb, const float* __restrict__ w1,
                     float* __restrict__ PQ, int b0){
    __shared__ float As[16][68];
    __shared__ float Bs[16][68];
    int bx = blockIdx.x & 15;      // col tile
    int by = blockIdx.x >> 4;      // row tile (0..31)
    int tid = threadIdx.x;
    int tm = tid >> 4, tn = tid & 15;
    const float* A0 = wemb + (size_t)b0*W_*H_;
    int colbase = bx*64;
    const float* Bbase = (colbase < DFF_) ? w1 : (w1 + (size_t)H_*DFF_);
    int bcol0 = (colbase < DFF_) ? colbase : (colbase - DFF_);
    float acc[4][4] = {{0.f}};
    int ar = tid >> 2, akq = tid & 3;
    int bkk = tid >> 4, bcq = tid & 15;
    const int ROWS = 4*W_;         // 2016
    for (int k0 = 0; k0 < H_; k0 += 16){
        {
            int gr = by*64 + ar;
            float4 av;
            if (gr < ROWS) av = *(const float4*)(A0 + (size_t)gr*H_ + k0 + akq*4);
            else av = make_float4(0.f,0.f,0.f,0.f);
            As[akq*4+0][ar] = av.x; As[akq*4+1][ar] = av.y;
            As[akq*4+2][ar] = av.z; As[akq*4+3][ar] = av.w;
        }
        {
            float4 bv = *(const float4*)(Bbase + (size_t)(k0+bkk)*DFF_ + bcol0 + bcq*4);
            Bs[bkk][bcq*4+0] = bv.x; Bs[bkk][bcq*4+1] = bv.y;
            Bs[bkk][bcq*4+2] = bv.z; Bs[bkk][bcq*4+3] = bv.w;
        }
        __syncthreads();
        #pragma unroll
        for (int kk = 0; kk < 16; kk++){
            float4 a = *(const float4*)&As[kk][tm*4];
            float4 bv = *(const float4*)&Bs[kk][tn*4];
            acc[0][0] += a.x*bv.x; acc[0][1] += a.x*bv.y; acc[0][2] += a.x*bv.z; acc[0][3] += a.x*bv.w;
            acc[1][0] += a.y*bv.x; acc[1][1] += a.y*bv.y; acc[1][2] += a.y*bv.z; acc[1][3] += a.y*bv.w;
            acc[2][0] += a.z*bv.x; acc[2][1] += a.z*bv.y; acc[2][2] += a.z*bv.z; acc[2][3] += a.z*bv.w;
            acc[3][0] += a.w*bv.x; acc[3][1] += a.w*bv.y; acc[3][2] += a.w*bv.z; acc[3][3] += a.w*bv.w;
        }
        __syncthreads();
    }
    #pragma unroll
    for (int r = 0; r < 4; r++){
        int gr = by*64 + tm*4 + r;
        if (gr < ROWS){
            float4 ov = make_float4(acc[r][0], acc[r][1], acc[r][2], acc[r][3]);
            *(float4*)(PQ + (size_t)gr*1024 + colbase + tn*4) = ov;
        }
    }
}

// ---------------- logits: one block per (bl, s); 4-way fp64 accum + wave-shuffle reduce ------
__global__ void k_logits(const float* __restrict__ PQ, const float* __restrict__ Mmat,
                         const float* __restrict__ cvec, const float* __restrict__ span_b1,
                         float* __restrict__ logits, float* __restrict__ outL, int b0){
    __shared__ float Ps[DFF_];
    __shared__ float hid[DFF_];
    __shared__ double redw[64];
    __shared__ float csh[E_];
    int blk = blockIdx.x;            // 4*W_ blocks
    int bl = blk / W_; int s = blk - bl*W_;
    int b = b0 + bl;
    int tid = threadIdx.x;
    int lane = tid & 63, wave = tid >> 6;
    int ee = tid & 15; int g = tid >> 4;   // 16 groups x 32 d
    float Mreg[32];
    {
        const float* Mp = Mmat + (size_t)b*DFF_*E_ + (size_t)(g*32)*E_ + ee;
        #pragma unroll
        for (int i = 0; i < 32; i++) Mreg[i] = Mp[(size_t)i*E_];
    }
    const float* P = PQ + ((size_t)(bl*W_ + s))*1024;
    for (int d = tid; d < DFF_; d += 256) Ps[d] = P[d] + span_b1[d];
    if (tid < E_) csh[tid] = cvec[b*E_ + tid];
    __syncthreads();
    int nsp = min(12, W_ - s);
    int nbase = rowstart_of(s);
    for (int i = 0; i < nsp; i++){
        int e = s + i;
        const float* Q = PQ + ((size_t)(bl*W_ + e))*1024 + DFF_;
        for (int d = tid; d < DFF_; d += 256){
            float h = Ps[d] + Q[d];
            hid[d] = h > 0.f ? h : 0.01f*h;
        }
        __syncthreads();
        {
            int d0 = g*32;
            double a0=0.0, a1=0.0, a2=0.0, a3=0.0;   // 4 chains break the serial FMA dep
            #pragma unroll
            for (int k = 0; k < 32; k += 4){
                a0 += (double)hid[d0+k+0]*(double)Mreg[k+0];
                a1 += (double)hid[d0+k+1]*(double)Mreg[k+1];
                a2 += (double)hid[d0+k+2]*(double)Mreg[k+2];
                a3 += (double)hid[d0+k+3]*(double)Mreg[k+3];
            }
            double acc = (a0+a1)+(a2+a3);
            double t = acc + __shfl_down(acc, 32, 64);
            t = t + __shfl_down(t, 16, 64);
            if (lane < 16) redw[wave*16 + lane] = t;
        }
        __syncthreads();
        if (tid < E_){
            double t = ((redw[tid] + redw[16+tid]) + (redw[32+tid] + redw[48+tid]))
                     + (double)csh[tid];
            float lg = (float)t;
            size_t oi = ((size_t)b*N_ + nbase + i)*E_ + tid;
            logits[oi] = lg;
            outL[oi] = lg;
        }
        __syncthreads();
    }
}

// ---------------- per-span best candidate + selected-region zeroing ----------------
__global__ void k_spanbest(const float* __restrict__ logits,
                           const int* __restrict__ starts, const int* __restrict__ ends,
                           u64* __restrict__ candS, float* __restrict__ outSel){
    int idx = blockIdx.x*256 + threadIdx.x;      // over B_*N_
    if (idx >= B_*N_) return;
    int b = idx / N_; int n = idx - b*N_;
    const float* lg = logits + (size_t)b*NE_ + (size_t)n*16;
    u64 best = ~0ull;
    for (int e = 0; e < 16; e++){
        float prob = 1.0f/(1.0f + expf(-lg[e]));
        if (prob > 0.5f){
            u32 key24 = (~__float_as_uint(prob)) & 0xFFFFFFu;
            u64 pk = ((u64)key24 << 24) | (u64)(u32)(n*16 + e);
            best = best < pk ? best : pk;
        }
    }
    int s = starts[n], e2 = ends[n];
    int len = e2 - s + 1;
    u64 packed = best;
    if (best != ~0ull)
        packed = best | ((u64)(u32)s << 48) | ((u64)(u32)(len-1) << 57);
    candS[idx] = packed;
    float* selp = outSel + (size_t)BNE_ + (size_t)b*NE_ + (size_t)n*16;
    float4 z = make_float4(0.f,0.f,0.f,0.f);
    *(float4*)(selp+0)  = z; *(float4*)(selp+4)  = z;
    *(float4*)(selp+8)  = z; *(float4*)(selp+12) = z;
}

// ---------------- greedy decode: wave-parallel prefix-OR rounds + serial pending -------------
// Per 64-chunk: tentative lanes = no overlap with coverage. A tentative lane not overlapping
// the union of EARLIER tentative lanes' masks accepts unconditionally (its only possible
// blockers are a subset of earlier tentatives). Exclusive prefix-OR via shfl_up scan (OR-scan
// needs no lane predicate: shfl_up returns own value for lane<delta). Accepted-mask union via
// shfl_xor butterfly -> coverage update. Remaining "pending" lanes (overlap an earlier
// tentative) are resolved with the serial scalar replay — exact: a round-accepted lane LATER
// than a pending lane can never overlap it (it would have been blocked itself).
__device__ __forceinline__ void decode_wave(const u64* sp, int n,
                                            float* __restrict__ outSel, int b){
    int lane = threadIdx.x & 63;
    u64 scov[8];
    #pragma unroll
    for (int k = 0; k < 8; k++) scov[k] = 0ull;
    int covcnt = 0;
    for (int base = 0; base < n; base += 64){
        int i = base + lane;
        bool has = i < n;
        u64 v = has ? sp[i] : ~0ull;
        int s   = (int)((v >> 48) & 0x1FFull);
        int len = (int)((v >> 57) & 0xFull) + 1;
        u32 c   = (u32)(v & 0xFFFFFFull);
        int w0 = s >> 6, sh0 = s & 63;
        int w1i = (w0 < 7) ? w0 + 1 : 7;
        u64 full = (1ull << len) - 1ull;
        u64 m0 = has ? (full << sh0) : 0ull;
        u64 m1 = (has && sh0 + len > 64) ? (full >> (64 - sh0)) : 0ull;
        u64 myc0 = 0ull, myc1 = 0ull;
        #pragma unroll
        for (int k = 0; k < 8; k++){
            if (w0  == k) myc0 = scov[k];
            if (w1i == k) myc1 = scov[k];
        }
        bool alive = has && (((myc0 & m0) | (myc1 & m1)) == 0ull);
        bool accept = false;
        u64 balv = __ballot(alive);
        if (balv){
            // exclusive prefix-OR of alive masks over 8 words
            u64 pm[8];
            #pragma unroll
            for (int k = 0; k < 8; k++){
                u64 t = 0ull;
                if (alive){
                    if (w0  == k) t |= m0;
                    if (w1i == k) t |= m1;
                }
                pm[k] = t;
            }
            #pragma unroll
            for (int st = 1; st < 64; st <<= 1){
                #pragma unroll
                for (int k = 0; k < 8; k++) pm[k] |= shflup_u64(pm[k], st);
            }
            u64 ex0 = 0ull, ex1 = 0ull;
            #pragma unroll
            for (int k = 0; k < 8; k++){
                u64 e = shflup_u64(pm[k], 1);
                e = (lane == 0) ? 0ull : e;
                if (w0  == k) ex0 = e;
                if (w1i == k) ex1 = e;
            }
            bool blocked = (((ex0 & m0) | (ex1 & m1)) != 0ull);
            bool newacc = alive && !blocked;
            accept = newacc;
            // union of accepted masks (mutually disjoint) -> coverage
            u64 am[8];
            #pragma unroll
            for (int k = 0; k < 8; k++){
                u64 t = 0ull;
                if (newacc){
                    if (w0  == k) t |= m0;
                    if (w1i == k) t |= m1;
                }
                am[k] = t;
            }
            #pragma unroll
            for (int st = 1; st < 64; st <<= 1){
                #pragma unroll
                for (int k = 0; k < 8; k++) am[k] |= shflxor_u64(am[k], st);
            }
            #pragma unroll
            for (int k = 0; k < 8; k++){
                covcnt += (int)__popcll(am[k]);
                scov[k] |= am[k];
            }
            // serial resolution of pending lanes (in rank order, vs live coverage)
            u64 pend = __ballot(alive && blocked);
            u32 vlo = (u32)v, vhi = (u32)(v >> 32);
            u64 accm = 0ull;
            while (pend){
                int j = (int)__builtin_ctzll(pend);
                pend &= pend - 1ull;
#if __has_builtin(__builtin_amdgcn_readlane)
                u32 jlo = (u32)__builtin_amdgcn_readlane((int)vlo, j);
                u32 jhi = (u32)__builtin_amdgcn_readlane((int)vhi, j);
#else
                u32 jlo = (u32)__shfl((int)vlo, j, 64);
                u32 jhi = (u32)__shfl((int)vhi, j, 64);
#endif
                u64 jv = ((u64)jhi << 32) | (u64)jlo;
                int js   = (int)((jv >> 48) & 0x1FFull);
                int jlen = (int)((jv >> 57) & 0xFull) + 1;
                int jw0 = js >> 6, jsh = js & 63;
                int jw1 = (jw0 < 7) ? jw0 + 1 : 7;
                u64 jfull = (1ull << jlen) - 1ull;
                u64 jm0 = jfull << jsh;
                u64 jm1 = (jsh + jlen > 64) ? (jfull >> (64 - jsh)) : 0ull;
                u64 c0 = 0ull, c1 = 0ull;
                #pragma unroll
                for (int k = 0; k < 8; k++){
                    if (jw0 == k) c0 = scov[k];
                    if (jw1 == k) c1 = scov[k];
                }
                bool ok = (((c0 & jm0) | (c1 & jm1)) == 0ull);
                u64 okm = ok ? ~0ull : 0ull;
                #pragma unroll
                for (int k = 0; k < 8; k++){
                    u64 add = 0ull;
                    if (jw0 == k) add |= jm0;
                    if (jw1 == k) add |= jm1;
                    scov[k] |= (add & okm);
                }
                covcnt += ok ? jlen : 0;
                accm |= (okm & (1ull << j));
            }
            if (((accm >> lane) & 1ull) != 0ull) accept = true;
        }
        if (accept)
            outSel[(size_t)BNE_ + (size_t)b*NE_ + (size_t)c] = 1.0f;
        if (covcnt >= W_) break;
    }
}

// ---------------- fused tail, LDS-resident: DP -> compact -> rank-sort -> decode -------------
__global__ __launch_bounds__(256) void k_tail(const u64* __restrict__ candS,
                                              float* __restrict__ outSel){
    __shared__ u64 cs[6032];          // candidate table, then compacted+sorted (+pad 16)
    __shared__ u64 Ma[512], Mb[512];  // DP ping-pong
    __shared__ u32 wtot[4];
    __shared__ int nsh;
    int b = blockIdx.x; int tid = threadIdx.x;
    int lane = tid & 63, wave = tid >> 6;
    const u64* cSg = candS + (size_t)b*N_;

    // ---- load table -> LDS (fully unrolled: 24 independent loads in flight) ----
    #pragma unroll
    for (int k = 0; k < 23; k++) cs[tid + k*256] = cSg[tid + k*256];
    { int i23 = tid + 23*256; if (i23 < N_) cs[i23] = cSg[i23]; }
    __syncthreads();

    // ---- Phase A: nested-dominance DP (11 rounds) ----
    for (int s = tid; s < 512; s += 256)
        Ma[s] = (s < W_) ? (cs[rowstart_of(s)] & MAXK48) : MAXK48;
    __syncthreads();
    u64* Mcur = Ma; u64* Mnext = Mb;
    for (int l = 2; l <= 12; l++){
        #pragma unroll
        for (int q = 0; q < 2; q++){
            int s = tid + q*256;          // 0..511
            u64 key = MAXK48; int idx = -1;
            if (s + l <= W_){ idx = rowstart_of(s) + (l-1); key = cs[idx] & MAXK48; }
            u64 a = Mcur[s];
            u64 bb = (s + 1 < 512) ? Mcur[s+1] : MAXK48;
            u64 dom = a < bb ? a : bb;
            if (idx >= 0 && dom < key) cs[idx] = ~0ull;      // pruned
            Mnext[s] = dom < key ? dom : key;
        }
        __syncthreads();
        u64* t = Mcur; Mcur = Mnext; Mnext = t;
    }

    // ---- Phase B: in-place compaction (blocked, register-staged) ----
    {
        int base = tid*PT_;
        u64 vv[PT_];
        u32 flags = 0; int cnt = 0;
        #pragma unroll
        for (int k = 0; k < PT_; k++){
            int i = base + k;
            u64 v = (i < N_) ? cs[i] : ~0ull;
            vv[k] = v;
            if (v != ~0ull){ flags |= (1u << k); cnt++; }
        }
        u32 inc = (u32)cnt;
        for (int d = 1; d < 64; d <<= 1){ u32 o = (u32)__shfl_up((int)inc, d, 64); if (lane >= d) inc += o; }
        if (lane == 63) wtot[wave] = inc;
        __syncthreads();
        u32 woffs = 0;
        for (int w = 0; w < 4; w++) if (w < wave) woffs += wtot[w];
        u32 off = woffs + inc - (u32)cnt;
        if (tid == 255) nsh = (int)(woffs + inc);
        #pragma unroll
        for (int k = 0; k < PT_; k++){
            if (flags & (1u << k)) cs[off++] = vv[k];
        }
    }
    __syncthreads();
    int n = nsh;
    if (tid < 16) cs[n + tid] = ~0ull;     // pad for 16-wide batched reads
    __syncthreads();

    // ---- Phase C: rank-sort over low-48 keys ----
    if (n <= 1536){
        // fast path: <=6 owned elements in named registers; 16 loads in flight per batch
        u64 v0=~0ull,v1=~0ull,v2=~0ull,v3=~0ull,v4=~0ull,v5=~0ull;
        u64 k0=0,k1=0,k2=0,k3=0,k4=0,k5=0;
        if (tid        < n){ v0 = cs[tid];        k0 = v0 & MAXK48; }
        if (tid +  256 < n){ v1 = cs[tid +  256]; k1 = v1 & MAXK48; }
        if (tid +  512 < n){ v2 = cs[tid +  512]; k2 = v2 & MAXK48; }
        if (tid +  768 < n){ v3 = cs[tid +  768]; k3 = v3 & MAXK48; }
        if (tid + 1024 < n){ v4 = cs[tid + 1024]; k4 = v4 & MAXK48; }
        if (tid + 1280 < n){ v5 = cs[tid + 1280]; k5 = v5 & MAXK48; }
        u32 r0=0,r1=0,r2=0,r3=0,r4=0,r5=0;
        for (int j = 0; j < n; j += 16){
            u64 c0 = cs[j+ 0]&MAXK48, c1 = cs[j+ 1]&MAXK48, c2 = cs[j+ 2]&MAXK48, c3 = cs[j+ 3]&MAXK48;
            u64 c4 = cs[j+ 4]&MAXK48, c5 = cs[j+ 5]&MAXK48, c6 = cs[j+ 6]&MAXK48, c7 = cs[j+ 7]&MAXK48;
            u64 c8 = cs[j+ 8]&MAXK48, c9 = cs[j+ 9]&MAXK48, cA = cs[j+10]&MAXK48, cB = cs[j+11]&MAXK48;
            u64 cC = cs[j+12]&MAXK48, cD = cs[j+13]&MAXK48, cE = cs[j+14]&MAXK48, cF = cs[j+15]&MAXK48;
            r0 += (u32)(c0<k0)+(u32)(c1<k0)+(u32)(c2<k0)+(u32)(c3<k0)+(u32)(c4<k0)+(u32)(c5<k0)+(u32)(c6<k0)+(u32)(c7<k0)
                + (u32)(c8<k0)+(u32)(c9<k0)+(u32)(cA<k0)+(u32)(cB<k0)+(u32)(cC<k0)+(u32)(cD<k0)+(u32)(cE<k0)+(u32)(cF<k0);
            r1 += (u32)(c0<k1)+(u32)(c1<k1)+(u32)(c2<k1)+(u32)(c3<k1)+(u32)(c4<k1)+(u32)(c5<k1)+(u32)(c6<k1)+(u32)(c7<k1)
                + (u32)(c8<k1)+(u32)(c9<k1)+(u32)(cA<k1)+(u32)(cB<k1)+(u32)(cC<k1)+(u32)(cD<k1)+(u32)(cE<k1)+(u32)(cF<k1);
            r2 += (u32)(c0<k2)+(u32)(c1<k2)+(u32)(c2<k2)+(u32)(c3<k2)+(u32)(c4<k2)+(u32)(c5<k2)+(u32)(c6<k2)+(u32)(c7<k2)
                + (u32)(c8<k2)+(u32)(c9<k2)+(u32)(cA<k2)+(u32)(cB<k2)+(u32)(cC<k2)+(u32)(cD<k2)+(u32)(cE<k2)+(u32)(cF<k2);
            r3 += (u32)(c0<k3)+(u32)(c1<k3)+(u32)(c2<k3)+(u32)(c3<k3)+(u32)(c4<k3)+(u32)(c5<k3)+(u32)(c6<k3)+(u32)(c7<k3)
                + (u32)(c8<k3)+(u32)(c9<k3)+(u32)(cA<k3)+(u32)(cB<k3)+(u32)(cC<k3)+(u32)(cD<k3)+(u32)(cE<k3)+(u32)(cF<k3);
            r4 += (u32)(c0<k4)+(u32)(c1<k4)+(u32)(c2<k4)+(u32)(c3<k4)+(u32)(c4<k4)+(u32)(c5<k4)+(u32)(c6<k4)+(u32)(c7<k4)
                + (u32)(c8<k4)+(u32)(c9<k4)+(u32)(cA<k4)+(u32)(cB<k4)+(u32)(cC<k4)+(u32)(cD<k4)+(u32)(cE<k4)+(u32)(cF<k4);
            r5 += (u32)(c0<k5)+(u32)(c1<k5)+(u32)(c2<k5)+(u32)(c3<k5)+(u32)(c4<k5)+(u32)(c5<k5)+(u32)(c6<k5)+(u32)(c7<k5)
                + (u32)(c8<k5)+(u32)(c9<k5)+(u32)(cA<k5)+(u32)(cB<k5)+(u32)(cC<k5)+(u32)(cD<k5)+(u32)(cE<k5)+(u32)(cF<k5);
        }
        __syncthreads();
        if (tid        < n) cs[r0] = v0;
        if (tid +  256 < n) cs[r1] = v1;
        if (tid +  512 < n) cs[r2] = v2;
        if (tid +  768 < n) cs[r3] = v3;
        if (tid + 1024 < n) cs[r4] = v4;
        if (tid + 1280 < n) cs[r5] = v5;
        __syncthreads();
    } else {
        // generic path (never expected; kept for correctness)
        u64 vv[PT_]; u32 rr[PT_];
        #pragma unroll
        for (int k = 0; k < PT_; k++){ vv[k] = ~0ull; rr[k] = 0; }
        #pragma unroll
        for (int k = 0; k < PT_; k++){
            int i = tid + (k << 8);
            if (i < n){
                u64 v = cs[i];
                vv[k] = v;
                u64 ki = v & MAXK48;
                u32 r = 0;
                for (int j = 0; j < n; j += 8){
                    u64 c0 = cs[j+0]&MAXK48, c1 = cs[j+1]&MAXK48;
                    u64 c2 = cs[j+2]&MAXK48, c3 = cs[j+3]&MAXK48;
                    u64 c4 = cs[j+4]&MAXK48, c5 = cs[j+5]&MAXK48;
                    u64 c6 = cs[j+6]&MAXK48, c7 = cs[j+7]&MAXK48;
                    r += (u32)(c0<ki) + (u32)(c1<ki) + (u32)(c2<ki) + (u32)(c3<ki)
                       + (u32)(c4<ki) + (u32)(c5<ki) + (u32)(c6<ki) + (u32)(c7<ki);
                }
                rr[k] = r;
            }
        }
        __syncthreads();
        #pragma unroll
        for (int k = 0; k < PT_; k++){
            int i = tid + (k << 8);
            if (i < n) cs[rr[k]] = vv[k];
        }
        __syncthreads();
    }

    // ---- Phase D: decode on wave 0, LDS-resident stream ----
    if (wave == 0) decode_wave(cs, n, outSel, b);
}

extern "C" void kernel_launch(void* const* d_in, const int* in_sizes, int n_in,
                              void* d_out, int out_size, void* d_ws, size_t ws_size,
                              hipStream_t stream){
    const float* hs        = (const float*)d_in[0];
    const float* ent_w1    = (const float*)d_in[1];
    const float* ent_b1    = (const float*)d_in[2];
    const float* ent_w2    = (const float*)d_in[3];
    const float* ent_b2    = (const float*)d_in[4];
    const float* span_w1   = (const float*)d_in[5];
    const float* span_b1   = (const float*)d_in[6];
    const float* span_w2   = (const float*)d_in[7];
    const float* span_b2   = (const float*)d_in[8];
    const int*  text_mask  = (const int*)d_in[9];
    const int*  ent_mask   = (const int*)d_in[10];
    const int*  word_index = (const int*)d_in[11];
    float* out = (float*)d_out;

    // ---- workspace (~24.5 MB peak; candS overlays dead wemb) ----
    char* wsbase = (char*)d_ws; size_t off = 0;
    auto alloc = [&](size_t bytes)->void*{ void* p = wsbase + off; off = (off + bytes + 255) & ~(size_t)255; return p; };
    char*  region1 = (char*)alloc((size_t)B_*W_*H_*4);    // 12,386,304 B
    float* wemb   = (float*)region1;                       // phase 1
    u64*   candS  = (u64*)region1;                         // phase 2: 382,848 B
    int*   tok    = (int*)  alloc((size_t)B_*W_*4*4);
    int*   tokc   = (int*)  alloc((size_t)B_*W_*4);
    float* PQ     = (float*)alloc((size_t)4*W_*1024*4);    // 8,257,536 B (4 batches/pass)
    float* logits = (float*)alloc((size_t)BNE_*4);         // 3,062,784 B
    int*   entpos = (int*)  alloc((size_t)B_*E_*4);
    float* entvec = (float*)alloc((size_t)B_*E_*H_*4);
    float* Mmat   = (float*)alloc((size_t)B_*DFF_*E_*4);
    float* cvec   = (float*)alloc((size_t)B_*E_*4);
    int*   starts = (int*)  alloc((size_t)N_*4);
    int*   ends   = (int*)  alloc((size_t)N_*4);

    k_prolog<<<9,256,0,stream>>>(ent_mask, entpos, starts, ends, tokc);
    k_toklist<<<(B_*L_+255)/256,256,0,stream>>>(text_mask, word_index, tok, tokc);
    k_poolsort<<<B_*W_,256,0,stream>>>(hs, tok, tokc, wemb);
    k_ent<<<B_*E_,256,0,stream>>>(hs, entpos, ent_w1, ent_b1, ent_w2, ent_b2, entvec);
    k_Mc<<<257,256,0,stream>>>(span_w2, span_b2, entvec, Mmat, cvec);
    for (int b0 = 0; b0 < B_; b0 += 4){
        k_pq<<<512,256,0,stream>>>(wemb, span_w1, PQ, b0);
        k_logits<<<4*W_,256,0,stream>>>(PQ, Mmat, cvec, span_b1, logits, out, b0);
    }
    // wemb dead from here; region1 hosts candS
    k_spanbest<<<(B_*N_+255)/256,256,0,stream>>>(logits, starts, ends, candS, out);
    k_tail<<<B_,256,0,stream>>>(candS, out);
}

// Round 7
// 432.305 us; speedup vs baseline: 1.3920x; 1.1278x over previous
//
#include <hip/hip_runtime.h>
#include <hip/hip_bf16.h>
#include <stdint.h>

#define B_ 8
#define L_ 1024
#define H_ 768
#define E_ 16
#define W_ 504
#define DFF_ 512
#define N_ 5982
#define NE_ (N_*E_)    // 95712 candidates per batch
#define BNE_ (B_*NE_)  // 765696
#define MAXK48 0x0000FFFFFFFFFFFFull
#define PT_ 24         // per-thread elements in generic sort path: 24*256 = 6144 >= N_

typedef unsigned long long u64;
typedef unsigned int u32;

__device__ __forceinline__ int rowstart_of(int s){
    int s0 = W_ - 11; // 493
    if (s <= s0) return 12*s;
    int t = s - s0;
    return 12*s0 + t*11 - (t*(t-1))/2;
}

__device__ __forceinline__ u64 shflup_u64(u64 x, int d){
    u32 lo = (u32)__shfl_up((int)(u32)x, d, 64);
    u32 hi = (u32)__shfl_up((int)(u32)(x >> 32), d, 64);
    return ((u64)hi << 32) | (u64)lo;
}
__device__ __forceinline__ u64 shflxor_u64(u64 x, int m){
    u32 lo = (u32)__shfl_xor((int)(u32)x, m, 64);
    u32 hi = (u32)__shfl_xor((int)(u32)(x >> 32), m, 64);
    return ((u64)hi << 32) | (u64)lo;
}

// ---------------- prolog: span tables + tokc zero (block 8), parallel entpos (blocks 0..7) ----
__global__ void k_prolog(const int* __restrict__ ent_mask, int* __restrict__ ent_pos,
                         int* __restrict__ starts, int* __restrict__ ends,
                         int* __restrict__ tokc){
    int blk = blockIdx.x; int tid = threadIdx.x;
    if (blk == 8){
        for (int s = tid; s < W_; s += 256){
            int rs = rowstart_of(s);
            int cnt = min(12, W_ - s);
            for (int i = 0; i < cnt; i++){ starts[rs+i] = s; ends[rs+i] = s+i; }
        }
        for (int i = tid; i < B_*W_; i += 256) tokc[i] = 0;
        return;
    }
    __shared__ u32 wt[4]; __shared__ u32 cbase;
    int b = blk;
    int lane = tid & 63, wave = tid >> 6;
    if (tid == 0) cbase = 0;
    __syncthreads();
    for (int base = 0; base < L_; base += 256){
        int l = base + tid;
        bool f = (ent_mask[b*L_ + l] == 1);
        u64 bal = __ballot(f);
        if (lane == 0) wt[wave] = (u32)__popcll(bal);
        __syncthreads();
        u32 pre = cbase;
        for (int w = 0; w < 4; w++) if (w < wave) pre += wt[w];
        if (f){
            u32 rank = pre + (u32)__popcll(bal & ((1ull<<lane)-1ull));
            if (rank < E_) ent_pos[b*E_ + rank] = l;
        }
        __syncthreads();
        if (tid == 0){ u32 r = cbase; for (int w = 0; w < 4; w++) r += wt[w]; cbase = r; }
        __syncthreads();
    }
    u32 totEnt = cbase;
    if (totEnt >= E_) return;                 // block-uniform
    for (int base = 0; base < L_; base += 256){
        int l = base + tid;
        bool f = (ent_mask[b*L_ + l] != 1);
        u64 bal = __ballot(f);
        if (lane == 0) wt[wave] = (u32)__popcll(bal);
        __syncthreads();
        u32 pre = cbase;
        for (int w = 0; w < 4; w++) if (w < wave) pre += wt[w];
        if (f){
            u32 rank = pre + (u32)__popcll(bal & ((1ull<<lane)-1ull));
            if (rank < E_) ent_pos[b*E_ + rank] = l;
        }
        __syncthreads();
        if (tid == 0){ u32 r = cbase; for (int w = 0; w < 4; w++) r += wt[w]; cbase = r; }
        __syncthreads();
    }
}

// ---------------- token lists: parallel build ----------------
__global__ void k_toklist(const int* __restrict__ tm, const int* __restrict__ wi,
                          int* __restrict__ tok, int* __restrict__ tokc){
    int i = blockIdx.x*256 + threadIdx.x;
    if (i >= B_*L_) return;
    int w = wi[i];
    if (tm[i] == 1 && w >= 0 && w < W_){
        int b = i / L_;
        int bw = b*W_ + w;
        int pos = atomicAdd(&tokc[bw], 1);
        if (pos < 4) tok[bw*4 + pos] = i - b*L_;
    }
}

// ---------------- fused per-word sort + mean pooling (one block per (b,w)) ----------------
__global__ void k_poolsort(const float* __restrict__ hs, const int* __restrict__ tok,
                           const int* __restrict__ tokc, float* __restrict__ wemb){
    __shared__ int stok[4]; __shared__ int scnt;
    int bw = blockIdx.x;                       // B_*W_
    int b = bw / W_;
    int tid = threadIdx.x;
    if (tid == 0){
        int c = tokc[bw]; int cc = min(c, 4);
        int v[4];
        for (int k = 0; k < cc; k++) v[k] = tok[bw*4 + k];
        for (int a = 1; a < cc; a++){ int x = v[a]; int j = a-1; while (j >= 0 && v[j] > x){ v[j+1] = v[j]; j--; } v[j+1] = x; }
        for (int k = 0; k < cc; k++) stok[k] = v[k];
        scnt = c;
    }
    __syncthreads();
    int c = scnt; int cc = min(c, 4);
    float denom = (float)max(c, 1);
    for (int h = tid; h < H_; h += 256){
        double s = 0.0;
        for (int k = 0; k < cc; k++)
            s += (double)hs[((size_t)(b*L_ + stok[k]))*H_ + h];
        wemb[(size_t)bw*H_ + h] = (float)(s / (double)denom);
    }
}

// ---------------- entity MLP layer 1 (one output/thread; deep load pipeline) ----------------
__global__ void k_ent1(const float* __restrict__ hs, const int* __restrict__ ent_pos,
                       const float* __restrict__ w1, const float* __restrict__ b1,
                       float* __restrict__ hidg){
    __shared__ float x[H_];
    int blk = blockIdx.x;            // 256 blocks: be*2 + half
    int be = blk >> 1; int half = blk & 1;
    int b = be >> 4;
    int tid = threadIdx.x;
    int pos = ent_pos[be];
    const float* xp = hs + ((size_t)b*L_ + pos)*H_;
    for (int j = tid; j < H_; j += 256) x[j] = xp[j];
    __syncthreads();
    int d = half*256 + tid;
    float a0=0.f,a1=0.f,a2=0.f,a3=0.f;
    const float* wp = w1 + d;
    #pragma unroll 8
    for (int h = 0; h < H_; h += 4){
        a0 += x[h+0]*wp[(size_t)(h+0)*DFF_];
        a1 += x[h+1]*wp[(size_t)(h+1)*DFF_];
        a2 += x[h+2]*wp[(size_t)(h+2)*DFF_];
        a3 += x[h+3]*wp[(size_t)(h+3)*DFF_];
    }
    float acc = ((a0+a1)+(a2+a3)) + b1[d];
    hidg[(size_t)be*DFF_ + d] = acc > 0.f ? acc : 0.01f*acc;
}

// ---------------- entity MLP layer 2 (one output/thread; deep load pipeline) ----------------
__global__ void k_ent2(const float* __restrict__ hidg,
                       const float* __restrict__ w2, const float* __restrict__ b2,
                       float* __restrict__ ent_vec){
    __shared__ float hsd[DFF_];
    int blk = blockIdx.x;            // 384 blocks: be*3 + third
    int be = blk / 3; int third = blk % 3;
    int tid = threadIdx.x;
    const float* hp = hidg + (size_t)be*DFF_;
    for (int j = tid; j < DFF_; j += 256) hsd[j] = hp[j];
    __syncthreads();
    int j = third*256 + tid;
    float a0=0.f,a1=0.f,a2=0.f,a3=0.f;
    const float* wp = w2 + j;
    #pragma unroll 8
    for (int d = 0; d < DFF_; d += 4){
        a0 += hsd[d+0]*wp[(size_t)(d+0)*H_];
        a1 += hsd[d+1]*wp[(size_t)(d+1)*H_];
        a2 += hsd[d+2]*wp[(size_t)(d+2)*H_];
        a3 += hsd[d+3]*wp[(size_t)(d+3)*H_];
    }
    ent_vec[(size_t)be*H_ + j] = ((a0+a1)+(a2+a3)) + b2[j];
}

// ---------------- fused M + c: blocks 0..255 = M, block 256 = c (fp64, decode-critical) ------
__global__ void k_Mc(const float* __restrict__ span_w2, const float* __restrict__ span_b2,
                     const float* __restrict__ ent_vec, float* __restrict__ M,
                     float* __restrict__ cvec){
    int blk = blockIdx.x;
    if (blk == 256){
        int i = threadIdx.x;
        if (i < B_*E_){
            const float* ev = ent_vec + (size_t)i*H_;
            double acc = 0.0;
            for (int h = 0; h < H_; h++) acc += (double)span_b2[h]*(double)ev[h];
            cvec[i] = (float)acc;
        }
        return;
    }
    int b = blk/32; int dbase = (blk%32)*16;
    int tid = threadIdx.x; int d = dbase + (tid>>4); int e = tid&15;
    const float* ev = ent_vec + ((size_t)b*E_ + e)*H_;
    const float* wr = span_w2 + (size_t)d*H_;
    double p0=0.0, p1=0.0;
    for (int h = 0; h < H_; h += 2){
        p0 += (double)wr[h]*(double)ev[h];
        p1 += (double)wr[h+1]*(double)ev[h+1];
    }
    M[((size_t)b*DFF_ + d)*E_ + e] = (float)(p0+p1);
}

// ---------------- P/Q projection: tiled fp32 GEMM, 64x64 tiles, 4 batches per pass ----------
__global__ void k_pq(const float* __restrict__ wemb, const float* __restrict__ w1,
                     float* __restrict__ PQ, int b0){
    __shared__ float As[16][68];
    __shared__ float Bs[16][68];
    int bx = blockIdx.x & 15;      // col tile
    int by = blockIdx.x >> 4;      // row tile (0..31)
    int tid = threadIdx.x;
    int tm = tid >> 4, tn = tid & 15;
    const float* A0 = wemb + (size_t)b0*W_*H_;
    int colbase = bx*64;
    const float* Bbase = (colbase < DFF_) ? w1 : (w1 + (size_t)H_*DFF_);
    int bcol0 = (colbase < DFF_) ? colbase : (colbase - DFF_);
    float acc[4][4] = {{0.f}};
    int ar = tid >> 2, akq = tid & 3;
    int bkk = tid >> 4, bcq = tid & 15;
    const int ROWS = 4*W_;         // 2016
    for (int k0 = 0; k0 < H_; k0 += 16){
        {
            int gr = by*64 + ar;
            float4 av;
            if (gr < ROWS) av = *(const float4*)(A0 + (size_t)gr*H_ + k0 + akq*4);
            else av = make_float4(0.f,0.f,0.f,0.f);
            As[akq*4+0][ar] = av.x; As[akq*4+1][ar] = av.y;
            As[akq*4+2][ar] = av.z; As[akq*4+3][ar] = av.w;
        }
        {
            float4 bv = *(const float4*)(Bbase + (size_t)(k0+bkk)*DFF_ + bcol0 + bcq*4);
            Bs[bkk][bcq*4+0] = bv.x; Bs[bkk][bcq*4+1] = bv.y;
            Bs[bkk][bcq*4+2] = bv.z; Bs[bkk][bcq*4+3] = bv.w;
        }
        __syncthreads();
        #pragma unroll
        for (int kk = 0; kk < 16; kk++){
            float4 a = *(const float4*)&As[kk][tm*4];
            float4 bv = *(const float4*)&Bs[kk][tn*4];
            acc[0][0] += a.x*bv.x; acc[0][1] += a.x*bv.y; acc[0][2] += a.x*bv.z; acc[0][3] += a.x*bv.w;
            acc[1][0] += a.y*bv.x; acc[1][1] += a.y*bv.y; acc[1][2] += a.y*bv.z; acc[1][3] += a.y*bv.w;
            acc[2][0] += a.z*bv.x; acc[2][1] += a.z*bv.y; acc[2][2] += a.z*bv.z; acc[2][3] += a.z*bv.w;
            acc[3][0] += a.w*bv.x; acc[3][1] += a.w*bv.y; acc[3][2] += a.w*bv.z; acc[3][3] += a.w*bv.w;
        }
        __syncthreads();
    }
    #pragma unroll
    for (int r = 0; r < 4; r++){
        int gr = by*64 + tm*4 + r;
        if (gr < ROWS){
            float4 ov = make_float4(acc[r][0], acc[r][1], acc[r][2], acc[r][3]);
            *(float4*)(PQ + (size_t)gr*1024 + colbase + tn*4) = ov;
        }
    }
}

// ---------------- logits: one block per (bl, s); 4-way fp64 accum + wave-shuffle reduce ------
__global__ void k_logits(const float* __restrict__ PQ, const float* __restrict__ Mmat,
                         const float* __restrict__ cvec, const float* __restrict__ span_b1,
                         float* __restrict__ logits, float* __restrict__ outL, int b0){
    __shared__ float Ps[DFF_];
    __shared__ float hid[DFF_];
    __shared__ double redw[64];
    __shared__ float csh[E_];
    int blk = blockIdx.x;            // 4*W_ blocks
    int bl = blk / W_; int s = blk - bl*W_;
    int b = b0 + bl;
    int tid = threadIdx.x;
    int lane = tid & 63, wave = tid >> 6;
    int ee = tid & 15; int g = tid >> 4;   // 16 groups x 32 d
    float Mreg[32];
    {
        const float* Mp = Mmat + (size_t)b*DFF_*E_ + (size_t)(g*32)*E_ + ee;
        #pragma unroll
        for (int i = 0; i < 32; i++) Mreg[i] = Mp[(size_t)i*E_];
    }
    const float* P = PQ + ((size_t)(bl*W_ + s))*1024;
    for (int d = tid; d < DFF_; d += 256) Ps[d] = P[d] + span_b1[d];
    if (tid < E_) csh[tid] = cvec[b*E_ + tid];
    __syncthreads();
    int nsp = min(12, W_ - s);
    int nbase = rowstart_of(s);
    for (int i = 0; i < nsp; i++){
        int e = s + i;
        const float* Q = PQ + ((size_t)(bl*W_ + e))*1024 + DFF_;
        for (int d = tid; d < DFF_; d += 256){
            float h = Ps[d] + Q[d];
            hid[d] = h > 0.f ? h : 0.01f*h;
        }
        __syncthreads();
        {
            int d0 = g*32;
            double a0=0.0, a1=0.0, a2=0.0, a3=0.0;   // 4 chains break the serial FMA dep
            #pragma unroll
            for (int k = 0; k < 32; k += 4){
                a0 += (double)hid[d0+k+0]*(double)Mreg[k+0];
                a1 += (double)hid[d0+k+1]*(double)Mreg[k+1];
                a2 += (double)hid[d0+k+2]*(double)Mreg[k+2];
                a3 += (double)hid[d0+k+3]*(double)Mreg[k+3];
            }
            double acc = (a0+a1)+(a2+a3);
            double t = acc + __shfl_down(acc, 32, 64);
            t = t + __shfl_down(t, 16, 64);
            if (lane < 16) redw[wave*16 + lane] = t;
        }
        __syncthreads();
        if (tid < E_){
            double t = ((redw[tid] + redw[16+tid]) + (redw[32+tid] + redw[48+tid]))
                     + (double)csh[tid];
            float lg = (float)t;
            size_t oi = ((size_t)b*N_ + nbase + i)*E_ + tid;
            logits[oi] = lg;
            outL[oi] = lg;
        }
        __syncthreads();
    }
}

// ---------------- per-span best candidate + selected-region zeroing ----------------
__global__ void k_spanbest(const float* __restrict__ logits,
                           const int* __restrict__ starts, const int* __restrict__ ends,
                           u64* __restrict__ candS, float* __restrict__ outSel){
    int idx = blockIdx.x*256 + threadIdx.x;      // over B_*N_
    if (idx >= B_*N_) return;
    int b = idx / N_; int n = idx - b*N_;
    const float* lg = logits + (size_t)b*NE_ + (size_t)n*16;
    u64 best = ~0ull;
    for (int e = 0; e < 16; e++){
        float prob = 1.0f/(1.0f + expf(-lg[e]));
        if (prob > 0.5f){
            u32 key24 = (~__float_as_uint(prob)) & 0xFFFFFFu;
            u64 pk = ((u64)key24 << 24) | (u64)(u32)(n*16 + e);
            best = best < pk ? best : pk;
        }
    }
    int s = starts[n], e2 = ends[n];
    int len = e2 - s + 1;
    u64 packed = best;
    if (best != ~0ull)
        packed = best | ((u64)(u32)s << 48) | ((u64)(u32)(len-1) << 57);
    candS[idx] = packed;
    float* selp = outSel + (size_t)BNE_ + (size_t)b*NE_ + (size_t)n*16;
    float4 z = make_float4(0.f,0.f,0.f,0.f);
    *(float4*)(selp+0)  = z; *(float4*)(selp+4)  = z;
    *(float4*)(selp+8)  = z; *(float4*)(selp+12) = z;
}

// ---------------- greedy decode: wave-parallel prefix-OR rounds + serial pending -------------
__device__ __forceinline__ void decode_wave(const u64* sp, int n,
                                            float* __restrict__ outSel, int b){
    int lane = threadIdx.x & 63;
    u64 scov[8];
    #pragma unroll
    for (int k = 0; k < 8; k++) scov[k] = 0ull;
    int covcnt = 0;
    for (int base = 0; base < n; base += 64){
        int i = base + lane;
        bool has = i < n;
        u64 v = has ? sp[i] : ~0ull;
        int s   = (int)((v >> 48) & 0x1FFull);
        int len = (int)((v >> 57) & 0xFull) + 1;
        u32 c   = (u32)(v & 0xFFFFFFull);
        int w0 = s >> 6, sh0 = s & 63;
        int w1i = (w0 < 7) ? w0 + 1 : 7;
        u64 full = (1ull << len) - 1ull;
        u64 m0 = has ? (full << sh0) : 0ull;
        u64 m1 = (has && sh0 + len > 64) ? (full >> (64 - sh0)) : 0ull;
        u64 myc0 = 0ull, myc1 = 0ull;
        #pragma unroll
        for (int k = 0; k < 8; k++){
            if (w0  == k) myc0 = scov[k];
            if (w1i == k) myc1 = scov[k];
        }
        bool alive = has && (((myc0 & m0) | (myc1 & m1)) == 0ull);
        bool accept = false;
        u64 balv = __ballot(alive);
        if (balv){
            u64 pm[8];
            #pragma unroll
            for (int k = 0; k < 8; k++){
                u64 t = 0ull;
                if (alive){
                    if (w0  == k) t |= m0;
                    if (w1i == k) t |= m1;
                }
                pm[k] = t;
            }
            #pragma unroll
            for (int st = 1; st < 64; st <<= 1){
                #pragma unroll
                for (int k = 0; k < 8; k++) pm[k] |= shflup_u64(pm[k], st);
            }
            u64 ex0 = 0ull, ex1 = 0ull;
            #pragma unroll
            for (int k = 0; k < 8; k++){
                u64 e = shflup_u64(pm[k], 1);
                e = (lane == 0) ? 0ull : e;
                if (w0  == k) ex0 = e;
                if (w1i == k) ex1 = e;
            }
            bool blocked = (((ex0 & m0) | (ex1 & m1)) != 0ull);
            bool newacc = alive && !blocked;
            accept = newacc;
            u64 am[8];
            #pragma unroll
            for (int k = 0; k < 8; k++){
                u64 t = 0ull;
                if (newacc){
                    if (w0  == k) t |= m0;
                    if (w1i == k) t |= m1;
                }
                am[k] = t;
            }
            #pragma unroll
            for (int st = 1; st < 64; st <<= 1){
                #pragma unroll
                for (int k = 0; k < 8; k++) am[k] |= shflxor_u64(am[k], st);
            }
            #pragma unroll
            for (int k = 0; k < 8; k++){
                covcnt += (int)__popcll(am[k]);
                scov[k] |= am[k];
            }
            u64 pend = __ballot(alive && blocked);
            u32 vlo = (u32)v, vhi = (u32)(v >> 32);
            u64 accm = 0ull;
            while (pend){
                int j = (int)__builtin_ctzll(pend);
                pend &= pend - 1ull;
#if __has_builtin(__builtin_amdgcn_readlane)
                u32 jlo = (u32)__builtin_amdgcn_readlane((int)vlo, j);
                u32 jhi = (u32)__builtin_amdgcn_readlane((int)vhi, j);
#else
                u32 jlo = (u32)__shfl((int)vlo, j, 64);
                u32 jhi = (u32)__shfl((int)vhi, j, 64);
#endif
                u64 jv = ((u64)jhi << 32) | (u64)jlo;
                int js   = (int)((jv >> 48) & 0x1FFull);
                int jlen = (int)((jv >> 57) & 0xFull) + 1;
                int jw0 = js >> 6, jsh = js & 63;
                int jw1 = (jw0 < 7) ? jw0 + 1 : 7;
                u64 jfull = (1ull << jlen) - 1ull;
                u64 jm0 = jfull << jsh;
                u64 jm1 = (jsh + jlen > 64) ? (jfull >> (64 - jsh)) : 0ull;
                u64 c0 = 0ull, c1 = 0ull;
                #pragma unroll
                for (int k = 0; k < 8; k++){
                    if (jw0 == k) c0 = scov[k];
                    if (jw1 == k) c1 = scov[k];
                }
                bool ok = (((c0 & jm0) | (c1 & jm1)) == 0ull);
                u64 okm = ok ? ~0ull : 0ull;
                #pragma unroll
                for (int k = 0; k < 8; k++){
                    u64 add = 0ull;
                    if (jw0 == k) add |= jm0;
                    if (jw1 == k) add |= jm1;
                    scov[k] |= (add & okm);
                }
                covcnt += ok ? jlen : 0;
                accm |= (okm & (1ull << j));
            }
            if (((accm >> lane) & 1ull) != 0ull) accept = true;
        }
        if (accept)
            outSel[(size_t)BNE_ + (size_t)b*NE_ + (size_t)c] = 1.0f;
        if (covcnt >= W_) break;
    }
}

// ---------------- fused tail, LDS-resident: DP -> compact -> rank-sort -> decode -------------
__global__ __launch_bounds__(256) void k_tail(const u64* __restrict__ candS,
                                              float* __restrict__ outSel){
    __shared__ u64 cs[6032];          // candidate table, then compacted+sorted (+pad 16)
    __shared__ u64 Ma[512], Mb[512];  // DP ping-pong
    __shared__ u32 wtot[4];
    __shared__ int nsh;
    int b = blockIdx.x; int tid = threadIdx.x;
    int lane = tid & 63, wave = tid >> 6;
    const u64* cSg = candS + (size_t)b*N_;

    // ---- load table -> LDS (fully unrolled: 24 independent loads in flight) ----
    #pragma unroll
    for (int k = 0; k < 23; k++) cs[tid + k*256] = cSg[tid + k*256];
    { int i23 = tid + 23*256; if (i23 < N_) cs[i23] = cSg[i23]; }
    __syncthreads();

    // ---- Phase A: nested-dominance DP (11 rounds) ----
    for (int s = tid; s < 512; s += 256)
        Ma[s] = (s < W_) ? (cs[rowstart_of(s)] & MAXK48) : MAXK48;
    __syncthreads();
    u64* Mcur = Ma; u64* Mnext = Mb;
    for (int l = 2; l <= 12; l++){
        #pragma unroll
        for (int q = 0; q < 2; q++){
            int s = tid + q*256;          // 0..511
            u64 key = MAXK48; int idx = -1;
            if (s + l <= W_){ idx = rowstart_of(s) + (l-1); key = cs[idx] & MAXK48; }
            u64 a = Mcur[s];
            u64 bb = (s + 1 < 512) ? Mcur[s+1] : MAXK48;
            u64 dom = a < bb ? a : bb;
            if (idx >= 0 && dom < key) cs[idx] = ~0ull;      // pruned
            Mnext[s] = dom < key ? dom : key;
        }
        __syncthreads();
        u64* t = Mcur; Mcur = Mnext; Mnext = t;
    }

    // ---- Phase B: in-place compaction (blocked, register-staged) ----
    {
        int base = tid*PT_;
        u64 vv[PT_];
        u32 flags = 0; int cnt = 0;
        #pragma unroll
        for (int k = 0; k < PT_; k++){
            int i = base + k;
            u64 v = (i < N_) ? cs[i] : ~0ull;
            vv[k] = v;
            if (v != ~0ull){ flags |= (1u << k); cnt++; }
        }
        u32 inc = (u32)cnt;
        for (int d = 1; d < 64; d <<= 1){ u32 o = (u32)__shfl_up((int)inc, d, 64); if (lane >= d) inc += o; }
        if (lane == 63) wtot[wave] = inc;
        __syncthreads();
        u32 woffs = 0;
        for (int w = 0; w < 4; w++) if (w < wave) woffs += wtot[w];
        u32 off = woffs + inc - (u32)cnt;
        if (tid == 255) nsh = (int)(woffs + inc);
        #pragma unroll
        for (int k = 0; k < PT_; k++){
            if (flags & (1u << k)) cs[off++] = vv[k];
        }
    }
    __syncthreads();
    int n = nsh;
    if (tid < 16) cs[n + tid] = ~0ull;     // pad for 16-wide batched reads
    __syncthreads();

    // ---- Phase C: rank-sort over low-48 keys ----
    if (n <= 1536){
        // fast path: <=6 owned elements in named registers; 16 loads in flight per batch
        u64 v0=~0ull,v1=~0ull,v2=~0ull,v3=~0ull,v4=~0ull,v5=~0ull;
        u64 k0=0,k1=0,k2=0,k3=0,k4=0,k5=0;
        if (tid        < n){ v0 = cs[tid];        k0 = v0 & MAXK48; }
        if (tid +  256 < n){ v1 = cs[tid +  256]; k1 = v1 & MAXK48; }
        if (tid +  512 < n){ v2 = cs[tid +  512]; k2 = v2 & MAXK48; }
        if (tid +  768 < n){ v3 = cs[tid +  768]; k3 = v3 & MAXK48; }
        if (tid + 1024 < n){ v4 = cs[tid + 1024]; k4 = v4 & MAXK48; }
        if (tid + 1280 < n){ v5 = cs[tid + 1280]; k5 = v5 & MAXK48; }
        u32 r0=0,r1=0,r2=0,r3=0,r4=0,r5=0;
        for (int j = 0; j < n; j += 16){
            u64 c0 = cs[j+ 0]&MAXK48, c1 = cs[j+ 1]&MAXK48, c2 = cs[j+ 2]&MAXK48, c3 = cs[j+ 3]&MAXK48;
            u64 c4 = cs[j+ 4]&MAXK48, c5 = cs[j+ 5]&MAXK48, c6 = cs[j+ 6]&MAXK48, c7 = cs[j+ 7]&MAXK48;
            u64 c8 = cs[j+ 8]&MAXK48, c9 = cs[j+ 9]&MAXK48, cA = cs[j+10]&MAXK48, cB = cs[j+11]&MAXK48;
            u64 cC = cs[j+12]&MAXK48, cD = cs[j+13]&MAXK48, cE = cs[j+14]&MAXK48, cF = cs[j+15]&MAXK48;
            r0 += (u32)(c0<k0)+(u32)(c1<k0)+(u32)(c2<k0)+(u32)(c3<k0)+(u32)(c4<k0)+(u32)(c5<k0)+(u32)(c6<k0)+(u32)(c7<k0)
                + (u32)(c8<k0)+(u32)(c9<k0)+(u32)(cA<k0)+(u32)(cB<k0)+(u32)(cC<k0)+(u32)(cD<k0)+(u32)(cE<k0)+(u32)(cF<k0);
            r1 += (u32)(c0<k1)+(u32)(c1<k1)+(u32)(c2<k1)+(u32)(c3<k1)+(u32)(c4<k1)+(u32)(c5<k1)+(u32)(c6<k1)+(u32)(c7<k1)
                + (u32)(c8<k1)+(u32)(c9<k1)+(u32)(cA<k1)+(u32)(cB<k1)+(u32)(cC<k1)+(u32)(cD<k1)+(u32)(cE<k1)+(u32)(cF<k1);
            r2 += (u32)(c0<k2)+(u32)(c1<k2)+(u32)(c2<k2)+(u32)(c3<k2)+(u32)(c4<k2)+(u32)(c5<k2)+(u32)(c6<k2)+(u32)(c7<k2)
                + (u32)(c8<k2)+(u32)(c9<k2)+(u32)(cA<k2)+(u32)(cB<k2)+(u32)(cC<k2)+(u32)(cD<k2)+(u32)(cE<k2)+(u32)(cF<k2);
            r3 += (u32)(c0<k3)+(u32)(c1<k3)+(u32)(c2<k3)+(u32)(c3<k3)+(u32)(c4<k3)+(u32)(c5<k3)+(u32)(c6<k3)+(u32)(c7<k3)
                + (u32)(c8<k3)+(u32)(c9<k3)+(u32)(cA<k3)+(u32)(cB<k3)+(u32)(cC<k3)+(u32)(cD<k3)+(u32)(cE<k3)+(u32)(cF<k3);
            r4 += (u32)(c0<k4)+(u32)(c1<k4)+(u32)(c2<k4)+(u32)(c3<k4)+(u32)(c4<k4)+(u32)(c5<k4)+(u32)(c6<k4)+(u32)(c7<k4)
                + (u32)(c8<k4)+(u32)(c9<k4)+(u32)(cA<k4)+(u32)(cB<k4)+(u32)(cC<k4)+(u32)(cD<k4)+(u32)(cE<k4)+(u32)(cF<k4);
            r5 += (u32)(c0<k5)+(u32)(c1<k5)+(u32)(c2<k5)+(u32)(c3<k5)+(u32)(c4<k5)+(u32)(c5<k5)+(u32)(c6<k5)+(u32)(c7<k5)
                + (u32)(c8<k5)+(u32)(c9<k5)+(u32)(cA<k5)+(u32)(cB<k5)+(u32)(cC<k5)+(u32)(cD<k5)+(u32)(cE<k5)+(u32)(cF<k5);
        }
        __syncthreads();
        if (tid        < n) cs[r0] = v0;
        if (tid +  256 < n) cs[r1] = v1;
        if (tid +  512 < n) cs[r2] = v2;
        if (tid +  768 < n) cs[r3] = v3;
        if (tid + 1024 < n) cs[r4] = v4;
        if (tid + 1280 < n) cs[r5] = v5;
        __syncthreads();
    } else {
        // generic path (never expected; kept for correctness)
        u64 vv[PT_]; u32 rr[PT_];
        #pragma unroll
        for (int k = 0; k < PT_; k++){ vv[k] = ~0ull; rr[k] = 0; }
        #pragma unroll
        for (int k = 0; k < PT_; k++){
            int i = tid + (k << 8);
            if (i < n){
                u64 v = cs[i];
                vv[k] = v;
                u64 ki = v & MAXK48;
                u32 r = 0;
                for (int j = 0; j < n; j += 8){
                    u64 c0 = cs[j+0]&MAXK48, c1 = cs[j+1]&MAXK48;
                    u64 c2 = cs[j+2]&MAXK48, c3 = cs[j+3]&MAXK48;
                    u64 c4 = cs[j+4]&MAXK48, c5 = cs[j+5]&MAXK48;
                    u64 c6 = cs[j+6]&MAXK48, c7 = cs[j+7]&MAXK48;
                    r += (u32)(c0<ki) + (u32)(c1<ki) + (u32)(c2<ki) + (u32)(c3<ki)
                       + (u32)(c4<ki) + (u32)(c5<ki) + (u32)(c6<ki) + (u32)(c7<ki);
                }
                rr[k] = r;
            }
        }
        __syncthreads();
        #pragma unroll
        for (int k = 0; k < PT_; k++){
            int i = tid + (k << 8);
            if (i < n) cs[rr[k]] = vv[k];
        }
        __syncthreads();
    }

    // ---- Phase D: decode on wave 0, LDS-resident stream ----
    if (wave == 0) decode_wave(cs, n, outSel, b);
}

extern "C" void kernel_launch(void* const* d_in, const int* in_sizes, int n_in,
                              void* d_out, int out_size, void* d_ws, size_t ws_size,
                              hipStream_t stream){
    const float* hs        = (const float*)d_in[0];
    const float* ent_w1    = (const float*)d_in[1];
    const float* ent_b1    = (const float*)d_in[2];
    const float* ent_w2    = (const float*)d_in[3];
    const float* ent_b2    = (const float*)d_in[4];
    const float* span_w1   = (const float*)d_in[5];
    const float* span_b1   = (const float*)d_in[6];
    const float* span_w2   = (const float*)d_in[7];
    const float* span_b2   = (const float*)d_in[8];
    const int*  text_mask  = (const int*)d_in[9];
    const int*  ent_mask   = (const int*)d_in[10];
    const int*  word_index = (const int*)d_in[11];
    float* out = (float*)d_out;

    // ---- workspace (~24.8 MB peak; candS overlays dead wemb) ----
    char* wsbase = (char*)d_ws; size_t off = 0;
    auto alloc = [&](size_t bytes)->void*{ void* p = wsbase + off; off = (off + bytes + 255) & ~(size_t)255; return p; };
    char*  region1 = (char*)alloc((size_t)B_*W_*H_*4);    // 12,386,304 B
    float* wemb   = (float*)region1;                       // phase 1
    u64*   candS  = (u64*)region1;                         // phase 2: 382,848 B
    int*   tok    = (int*)  alloc((size_t)B_*W_*4*4);
    int*   tokc   = (int*)  alloc((size_t)B_*W_*4);
    float* PQ     = (float*)alloc((size_t)4*W_*1024*4);    // 8,257,536 B (4 batches/pass)
    float* logits = (float*)alloc((size_t)BNE_*4);         // 3,062,784 B
    int*   entpos = (int*)  alloc((size_t)B_*E_*4);
    float* hidg   = (float*)alloc((size_t)B_*E_*DFF_*4);   // 262,144 B
    float* entvec = (float*)alloc((size_t)B_*E_*H_*4);
    float* Mmat   = (float*)alloc((size_t)B_*DFF_*E_*4);
    float* cvec   = (float*)alloc((size_t)B_*E_*4);
    int*   starts = (int*)  alloc((size_t)N_*4);
    int*   ends   = (int*)  alloc((size_t)N_*4);

    k_prolog<<<9,256,0,stream>>>(ent_mask, entpos, starts, ends, tokc);
    k_toklist<<<(B_*L_+255)/256,256,0,stream>>>(text_mask, word_index, tok, tokc);
    k_poolsort<<<B_*W_,256,0,stream>>>(hs, tok, tokc, wemb);
    k_ent1<<<B_*E_*2,256,0,stream>>>(hs, entpos, ent_w1, ent_b1, hidg);
    k_ent2<<<B_*E_*3,256,0,stream>>>(hidg, ent_w2, ent_b2, entvec);
    k_Mc<<<257,256,0,stream>>>(span_w2, span_b2, entvec, Mmat, cvec);
    for (int b0 = 0; b0 < B_; b0 += 4){
        k_pq<<<512,256,0,stream>>>(wemb, span_w1, PQ, b0);
        k_logits<<<4*W_,256,0,stream>>>(PQ, Mmat, cvec, span_b1, logits, out, b0);
    }
    // wemb dead from here; region1 hosts candS
    k_spanbest<<<(B_*N_+255)/256,256,0,stream>>>(logits, starts, ends, candS, out);
    k_tail<<<B_,256,0,stream>>>(candS, out);
}